// Round 3
// baseline (1473.334 us; speedup 1.0000x reference)
//
#include <hip/hip_runtime.h>
#include <float.h>
#include <math.h>

#define BINS 2048
#define DSTN 8
#define STEPF 1e-5f
#define NPART 1024
#define MAXST 4096

struct Ws {
  float pmin[NPART];
  float pmax[NPART];
  float min_val, max_val, bin_width, safe_bw;
  int   n_states;
  int   pad[3];
  unsigned int hist[BINS];
  float histf[BINS];
  float norms[MAXST];
  int2  states[MAXST];
};

// ---------------- Pass 1: block-partial min/max ----------------
__global__ void __launch_bounds__(256) k_minmax(const float* __restrict__ x, long long n,
                                                Ws* __restrict__ ws) {
  long long n4 = n >> 2;
  float vmin = FLT_MAX, vmax = -FLT_MAX;
  const float4* __restrict__ x4 = (const float4*)x;
  long long stride = (long long)gridDim.x * blockDim.x;
  for (long long i = (long long)blockIdx.x * blockDim.x + threadIdx.x; i < n4; i += stride) {
    float4 v = x4[i];
    vmin = fminf(vmin, fminf(fminf(v.x, v.y), fminf(v.z, v.w)));
    vmax = fmaxf(vmax, fmaxf(fmaxf(v.x, v.y), fmaxf(v.z, v.w)));
  }
  for (long long i = (n4 << 2) + (long long)blockIdx.x * blockDim.x + threadIdx.x; i < n; i += stride) {
    float v = x[i];
    vmin = fminf(vmin, v); vmax = fmaxf(vmax, v);
  }
  for (int off = 32; off > 0; off >>= 1) {
    vmin = fminf(vmin, __shfl_down(vmin, off));
    vmax = fmaxf(vmax, __shfl_down(vmax, off));
  }
  __shared__ float smin[4], smax[4];
  int wid = threadIdx.x >> 6;
  if ((threadIdx.x & 63) == 0) { smin[wid] = vmin; smax[wid] = vmax; }
  __syncthreads();
  if (threadIdx.x == 0) {
    float a = smin[0], b = smax[0];
    int nw = (int)(blockDim.x >> 6);
    for (int w = 1; w < nw; ++w) { a = fminf(a, smin[w]); b = fmaxf(b, smax[w]); }
    ws->pmin[blockIdx.x] = a; ws->pmax[blockIdx.x] = b;
  }
}

// ---------------- Reduce partials, compute bin_width, zero hist ----------------
__global__ void __launch_bounds__(256) k_minmax_final(Ws* __restrict__ ws, int nparts) {
  __shared__ float smin[256], smax[256];
  int t = threadIdx.x;
  float vmin = FLT_MAX, vmax = -FLT_MAX;
  for (int i = t; i < nparts; i += 256) {
    vmin = fminf(vmin, ws->pmin[i]);
    vmax = fmaxf(vmax, ws->pmax[i]);
  }
  smin[t] = vmin; smax[t] = vmax;
  __syncthreads();
  for (int off = 128; off > 0; off >>= 1) {
    if (t < off) { smin[t] = fminf(smin[t], smin[t + off]); smax[t] = fmaxf(smax[t], smax[t + off]); }
    __syncthreads();
  }
  if (t == 0) {
    float mn = smin[0], mx = smax[0];
    ws->min_val = mn; ws->max_val = mx;
    float bw = (mx - mn) / (float)BINS;
    ws->bin_width = bw;
    ws->safe_bw = (bw == 0.0f) ? 1.0f : bw;
  }
  for (int i = t; i < BINS; i += 256) ws->hist[i] = 0u;
}

// ---------------- Pass 2: histogram (LDS-private then global flush) ----------------
__global__ void __launch_bounds__(256) k_hist(const float* __restrict__ x, long long n,
                                              Ws* __restrict__ ws) {
  __shared__ unsigned int lh[BINS];
  for (int i = threadIdx.x; i < BINS; i += 256) lh[i] = 0u;
  __syncthreads();
  float minv = ws->min_val;
  float sbw = ws->safe_bw;
  long long n4 = n >> 2;
  const float4* __restrict__ x4 = (const float4*)x;
  long long stride = (long long)gridDim.x * blockDim.x;
  for (long long i = (long long)blockIdx.x * blockDim.x + threadIdx.x; i < n4; i += stride) {
    float4 v = x4[i];
    int a = (int)floorf((v.x - minv) / sbw);
    int b = (int)floorf((v.y - minv) / sbw);
    int c = (int)floorf((v.z - minv) / sbw);
    int d = (int)floorf((v.w - minv) / sbw);
    a = min(BINS - 1, max(0, a));
    b = min(BINS - 1, max(0, b));
    c = min(BINS - 1, max(0, c));
    d = min(BINS - 1, max(0, d));
    atomicAdd(&lh[a], 1u);
    atomicAdd(&lh[b], 1u);
    atomicAdd(&lh[c], 1u);
    atomicAdd(&lh[d], 1u);
  }
  for (long long i = (n4 << 2) + (long long)blockIdx.x * blockDim.x + threadIdx.x; i < n; i += stride) {
    int a = (int)floorf((x[i] - minv) / sbw);
    a = min(BINS - 1, max(0, a));
    atomicAdd(&lh[a], 1u);
  }
  __syncthreads();
  for (int i = threadIdx.x; i < BINS; i += 256) {
    unsigned int c = lh[i];
    if (c) atomicAdd(&ws->hist[i], c);
  }
}

// chunked LDS read: one ds_read_b128 serves 4 consecutive bins; lane select via
// cndmask (no dynamic vector indexing -> no scratch)
__device__ __forceinline__ float cget(const float* cs, int& base, float4& v, int j) {
  int b = j & ~3;
  if (b != base) { v = *(const float4*)(cs + b); base = b; }
  float lo = (j & 1) ? v.y : v.x;
  float hi = (j & 1) ? v.w : v.z;
  return (j & 2) ? hi : lo;
}

// ---------------- Phase 3a: cumsum + event-driven greedy trajectory ----------------
// The (sb,eb) trajectory is independent of the norms (every changed iteration
// before the break is accepted): enumerate all candidate states; norms are
// evaluated in parallel afterwards (k_eval) and the break located in k_final.
// No-change runs of beta -= STEP are batch-jumped with exact fp32 binade
// arithmetic: within a binade fl(b-S) = b - d with constant d, and b - j*d is
// exactly representable (j*c < 2^24), so the synthesized sequence is
// bit-identical to stepping. Crossing/termination indices are verified against
// the actual fp32 comparisons.
__global__ void __launch_bounds__(256) k_search(Ws* __restrict__ ws) {
  __shared__ __align__(16) float csum[BINS];
  __shared__ float part[256];
  int t = threadIdx.x;

  float loc[8];
  float s = 0.0f;
  #pragma unroll
  for (int k = 0; k < 8; ++k) {
    float h = (float)ws->hist[t * 8 + k];
    ws->histf[t * 8 + k] = h;
    s += h;
    loc[k] = s;
  }
  part[t] = s;
  __syncthreads();
  for (int off = 1; off < 256; off <<= 1) {
    float add = (t >= off) ? part[t - off] : 0.0f;
    __syncthreads();
    part[t] += add;
    __syncthreads();
  }
  float excl = (t == 0) ? 0.0f : part[t - 1];
  #pragma unroll
  for (int k = 0; k < 8; ++k) csum[t * 8 + k] = excl + loc[k];
  __syncthreads();

  if (t != 0) return;

  const float S = STEPF;
  const float T = csum[BINS - 1];
  const float rcpT = 1.0f / T;

  float alpha = 0.0f, beta = 1.0f;
  int sb = 0, eb = BINS - 1;
  int nst = 0;

  // left pointer state
  float na = S;             // fl(0 + S)
  float vna = na * T;
  int lI = 0;
  int lbase = -4; float4 lv = make_float4(0, 0, 0, 0);
  while (lI < BINS && cget(csum, lbase, lv, lI) < vna) ++lI;

  // right pointer state
  int Rm = BINS - 1;
  int rbase = -4; float4 rv = make_float4(0, 0, 0, 0);
  float C = csum[BINS - 1];
  float Cn = C * rcpT;

  // binade cache
  unsigned cached_bid = 0xffffffffu;
  float binlo = 0.0f, d = 0.0f, rcp_d = 0.0f;

  int guard = 0;
  while (alpha < beta && ++guard < 200000) {
    float nb = beta - S;
    float vnb = nb * T;
    while (Rm >= 0 && cget(csum, rbase, rv, Rm) > vnb) --Rm;
    int l = lI < sb ? sb : (lI > eb ? eb : lI);
    int r = Rm < sb ? sb : (Rm > eb ? eb : Rm);
    int pl = l - sb, pr = eb - r;
    if (pl > pr) {
      // left take: one exact fp32 alpha step, state changes
      sb = l;
      alpha = na; na = alpha + S; vna = na * T;
      while (lI < BINS && cget(csum, lbase, lv, lI) < vna) ++lI;
      if (nst < MAXST) ws->states[nst] = make_int2(sb, eb);
      ++nst;
      continue;
    }
    beta = nb;
    if (pr > 0) {
      eb = r;
      C = cget(csum, rbase, rv, eb);
      Cn = C * rcpT;
      if (nst < MAXST) ws->states[nst] = make_int2(sb, eb);
      ++nst;
      continue;
    }
    if (sb >= eb) break;          // no further state changes possible
    if (!(alpha < beta)) break;

    // ---- batch jump within binade (exact fp32) ----
    unsigned bb = __float_as_uint(beta);
    unsigned bid = (bb & 0x7f800000u) - (((bb & 0x007fffffu) == 0u) ? 0x00800000u : 0u);
    if (bid != cached_bid) {
      cached_bid = bid;
      float bm1 = beta - S;       // actual fp32 step
      d = beta - bm1;             // Sterbenz: exact
      binlo = __uint_as_float(bid);
      rcp_d = (d > 0.0f) ? (1.0f / d) : 0.0f;
    }
    if (!(d > 0.0f)) continue;
    float brel = beta - binlo;    // exact (Sterbenz)
    int jmax = (int)floorf(brel * rcp_d);
    while (jmax >= 1 && (float)jmax * d > brel) --jmax;
    while ((float)(jmax + 1) * d <= brel) ++jmax;
    if (jmax < 1) continue;

    // ja: smallest j in [1, jmax] with fl((beta - j*d)*T) < C ; jmax+1 if none
    int ja = (int)((beta - Cn) * rcp_d) + 1;
    if (ja < 1) ja = 1;
    if (ja > jmax + 1) ja = jmax + 1;
    while (ja > 1) {
      float nbj = beta - (float)(ja - 1) * d;
      if (nbj * T < C) --ja; else break;
    }
    while (ja <= jmax) {
      float nbj = beta - (float)ja * d;
      if (nbj * T < C) break; else ++ja;
    }

    int jcand = (ja <= jmax) ? ja : jmax;
    // js: smallest j in [1, jcand] with beta - j*d <= alpha ; jcand+1 if none
    int js = jcand + 1;
    {
      float tgt = beta - (float)jcand * d;
      if (tgt <= alpha) {
        js = (int)((beta - alpha) * rcp_d);
        if (js < 1) js = 1;
        if (js > jcand) js = jcand;
        while (js > 1) {
          float nbj = beta - (float)(js - 1) * d;
          if (nbj <= alpha) --js; else break;
        }
        while (js <= jcand) {
          float nbj = beta - (float)js * d;
          if (nbj <= alpha) break; else ++js;
        }
      }
    }

    int jlim = (ja <= jmax) ? (ja - 1) : jmax;
    if (js <= jlim) {
      // termination before crossing/binade-end: steps 1..js all execute, then loop exits
      beta = beta - (float)js * d;
      continue;
    }
    if (ja > jmax) {
      // no crossing in this binade: jump to its bottom, continue in next binade
      beta = beta - (float)jmax * d;
      continue;
    }
    // crossing at step ja (executed, since js > ja-1): do step + event in this trip
    float nb2 = beta - (float)ja * d;      // == actual nb at the crossing iteration
    float vnb2 = nb2 * T;
    while (Rm >= 0 && cget(csum, rbase, rv, Rm) > vnb2) --Rm;
    int r2 = Rm < sb ? sb : (Rm > eb ? eb : Rm);
    beta = nb2;
    if (r2 < eb) {
      eb = r2;
      C = cget(csum, rbase, rv, eb);
      Cn = C * rcpT;
      if (nst < MAXST) ws->states[nst] = make_int2(sb, eb);
      ++nst;
    }
  }
  ws->n_states = (nst < MAXST) ? nst : MAXST;
}

// ---------------- Phase 3b: evaluate quantization error for all states ----------------
__global__ void __launch_bounds__(256) k_eval(Ws* __restrict__ ws) {
  int i = blockIdx.x;
  if (i >= ws->n_states) return;
  int2 st = ws->states[i];
  float bw = ws->bin_width;
  float cnt = (float)(st.y - st.x + 1);
  float w = bw * cnt / (float)DSTN;
  int t = threadIdx.x;
  if (w == 0.0f) {
    if (t == 0) ws->norms[i] = 0.0f;
    return;
  }
  float hw = 0.5f * w;
  float hw3 = hw * hw * hw;
  float nsb = (float)st.x;
  float sum = 0.0f;
  #pragma unroll
  for (int k = 0; k < 8; ++k) {
    int j = t + 256 * k;
    float h = ws->histf[j];
    float begin = ((float)j - nsb) * bw;
    float end = begin + bw;
    float db = fminf(fmaxf(floorf(begin / w), 0.0f), (float)(DSTN - 1));
    float de = fminf(fmaxf(floorf(end / w), 0.0f), (float)(DSTN - 1));
    float density = h / bw;
    float dbc = (db + 0.5f) * w;
    float a1 = begin - dbc;
    float n1 = density * (hw3 - a1 * a1 * a1) / 3.0f;
    float nmid = density * (hw3 + hw3) / 3.0f;
    float dec = de * w + hw;
    float a3 = end - dec;
    float n3 = density * (a3 * a3 * a3 + hw3) / 3.0f;
    sum += n1 + (de - db - 1.0f) * nmid + n3;
  }
  __shared__ float red[256];
  red[t] = sum;
  __syncthreads();
  for (int off = 128; off > 0; off >>= 1) {
    if (t < off) red[t] += red[t + off];
    __syncthreads();
  }
  if (t == 0) ws->norms[i] = red[0];
}

// ---------------- Phase 3c: first norm increase -> final range ----------------
__global__ void __launch_bounds__(256) k_final(Ws* __restrict__ ws, float* __restrict__ out) {
  __shared__ int sbrk[256];
  int N = ws->n_states;
  int t = threadIdx.x;
  int loc = 0x7fffffff;
  for (int i = t + 1; i < N; i += 256) {
    if (ws->norms[i] > ws->norms[i - 1]) loc = min(loc, i);
  }
  sbrk[t] = loc;
  __syncthreads();
  for (int off = 128; off > 0; off >>= 1) {
    if (t < off) sbrk[t] = min(sbrk[t], sbrk[t + off]);
    __syncthreads();
  }
  if (t == 0) {
    int sb, eb;
    if (N == 0) { sb = 0; eb = BINS - 1; }
    else {
      int ib = sbrk[0];
      int fi = (ib != 0x7fffffff) ? (ib - 1) : (N - 1);
      int2 st = ws->states[fi];
      sb = st.x; eb = st.y;
    }
    float minv = ws->min_val, bw = ws->bin_width;
    out[0] = minv + bw * (float)sb;
    out[1] = minv + bw * (float)(eb + 1);
  }
}

extern "C" void kernel_launch(void* const* d_in, const int* in_sizes, int n_in,
                              void* d_out, int out_size, void* d_ws, size_t ws_size,
                              hipStream_t stream) {
  const float* x = (const float*)d_in[0];
  long long n = (long long)in_sizes[0];
  Ws* ws = (Ws*)d_ws;
  float* out = (float*)d_out;

  k_minmax<<<NPART, 256, 0, stream>>>(x, n, ws);
  k_minmax_final<<<1, 256, 0, stream>>>(ws, NPART);
  k_hist<<<NPART, 256, 0, stream>>>(x, n, ws);
  k_search<<<1, 256, 0, stream>>>(ws);
  k_eval<<<MAXST, 256, 0, stream>>>(ws);
  k_final<<<1, 256, 0, stream>>>(ws, out);
}

// Round 4
// 999.104 us; speedup vs baseline: 1.4747x; 1.4747x over previous
//
#include <hip/hip_runtime.h>
#include <float.h>
#include <math.h>

#define BINS 2048
#define DSTN 8
#define STEPF 1e-5f
#define NPART 1024
#define MAXST 4096
#define NSEG 64
#define MINF 0x7fffffff

struct Ws {
  float pmin[NPART];
  float pmax[NPART];
  float min_val, max_val, bin_width, safe_bw;
  int   n_states;
  int   pad[3];
  unsigned int hist[BINS];
  float histf[BINS];
  float norms[MAXST];
  int2  states[MAXST];
};

// ---------------- Pass 1: block-partial min/max ----------------
__global__ void __launch_bounds__(256) k_minmax(const float* __restrict__ x, long long n,
                                                Ws* __restrict__ ws) {
  long long n4 = n >> 2;
  float vmin = FLT_MAX, vmax = -FLT_MAX;
  const float4* __restrict__ x4 = (const float4*)x;
  long long stride = (long long)gridDim.x * blockDim.x;
  for (long long i = (long long)blockIdx.x * blockDim.x + threadIdx.x; i < n4; i += stride) {
    float4 v = x4[i];
    vmin = fminf(vmin, fminf(fminf(v.x, v.y), fminf(v.z, v.w)));
    vmax = fmaxf(vmax, fmaxf(fmaxf(v.x, v.y), fmaxf(v.z, v.w)));
  }
  for (long long i = (n4 << 2) + (long long)blockIdx.x * blockDim.x + threadIdx.x; i < n; i += stride) {
    float v = x[i];
    vmin = fminf(vmin, v); vmax = fmaxf(vmax, v);
  }
  for (int off = 32; off > 0; off >>= 1) {
    vmin = fminf(vmin, __shfl_down(vmin, off));
    vmax = fmaxf(vmax, __shfl_down(vmax, off));
  }
  __shared__ float smin[4], smax[4];
  int wid = threadIdx.x >> 6;
  if ((threadIdx.x & 63) == 0) { smin[wid] = vmin; smax[wid] = vmax; }
  __syncthreads();
  if (threadIdx.x == 0) {
    float a = smin[0], b = smax[0];
    int nw = (int)(blockDim.x >> 6);
    for (int w = 1; w < nw; ++w) { a = fminf(a, smin[w]); b = fmaxf(b, smax[w]); }
    ws->pmin[blockIdx.x] = a; ws->pmax[blockIdx.x] = b;
  }
}

// ---------------- Reduce partials, compute bin_width, zero hist ----------------
__global__ void __launch_bounds__(256) k_minmax_final(Ws* __restrict__ ws, int nparts) {
  __shared__ float smin[256], smax[256];
  int t = threadIdx.x;
  float vmin = FLT_MAX, vmax = -FLT_MAX;
  for (int i = t; i < nparts; i += 256) {
    vmin = fminf(vmin, ws->pmin[i]);
    vmax = fmaxf(vmax, ws->pmax[i]);
  }
  smin[t] = vmin; smax[t] = vmax;
  __syncthreads();
  for (int off = 128; off > 0; off >>= 1) {
    if (t < off) { smin[t] = fminf(smin[t], smin[t + off]); smax[t] = fmaxf(smax[t], smax[t + off]); }
    __syncthreads();
  }
  if (t == 0) {
    float mn = smin[0], mx = smax[0];
    ws->min_val = mn; ws->max_val = mx;
    float bw = (mx - mn) / (float)BINS;
    ws->bin_width = bw;
    ws->safe_bw = (bw == 0.0f) ? 1.0f : bw;
  }
  for (int i = t; i < BINS; i += 256) ws->hist[i] = 0u;
}

// ---------------- Pass 2: histogram (LDS-private then global flush) ----------------
__global__ void __launch_bounds__(256) k_hist(const float* __restrict__ x, long long n,
                                              Ws* __restrict__ ws) {
  __shared__ unsigned int lh[BINS];
  for (int i = threadIdx.x; i < BINS; i += 256) lh[i] = 0u;
  __syncthreads();
  float minv = ws->min_val;
  float sbw = ws->safe_bw;
  long long n4 = n >> 2;
  const float4* __restrict__ x4 = (const float4*)x;
  long long stride = (long long)gridDim.x * blockDim.x;
  for (long long i = (long long)blockIdx.x * blockDim.x + threadIdx.x; i < n4; i += stride) {
    float4 v = x4[i];
    int a = (int)floorf((v.x - minv) / sbw);
    int b = (int)floorf((v.y - minv) / sbw);
    int c = (int)floorf((v.z - minv) / sbw);
    int d = (int)floorf((v.w - minv) / sbw);
    a = min(BINS - 1, max(0, a));
    b = min(BINS - 1, max(0, b));
    c = min(BINS - 1, max(0, c));
    d = min(BINS - 1, max(0, d));
    atomicAdd(&lh[a], 1u);
    atomicAdd(&lh[b], 1u);
    atomicAdd(&lh[c], 1u);
    atomicAdd(&lh[d], 1u);
  }
  for (long long i = (n4 << 2) + (long long)blockIdx.x * blockDim.x + threadIdx.x; i < n; i += stride) {
    int a = (int)floorf((x[i] - minv) / sbw);
    a = min(BINS - 1, max(0, a));
    atomicAdd(&lh[a], 1u);
  }
  __syncthreads();
  for (int i = threadIdx.x; i < BINS; i += 256) {
    unsigned int c = lh[i];
    if (c) atomicAdd(&ws->hist[i], c);
  }
}

// chunked int LDS read: one ds_read_b128 serves 4 consecutive entries
__device__ __forceinline__ int iget(const int* arr, int& base, int4& v, int j) {
  int b = j & ~3;
  if (b != base) { v = *(const int4*)(arr + b); base = b; }
  int lo = (j & 1) ? v.y : v.x;
  int hi = (j & 1) ? v.w : v.z;
  return (j & 2) ? hi : lo;
}

// ---------------- Phase 3a: cumsum + parallel schedules + integer merge ----------------
// The (sb,eb) trajectory is independent of the norms; additionally the alpha
// sequence A[k] (after k left-takes) and beta sequence B[m] (after m right
// steps) are fixed fp32 sequences independent of the interleave. So:
//   ltab[k]   = searchsorted_left(csum, fl(A[k+1]*T))  (per-k, parallel)
//   mcross[b] = smallest m with fl(B[m+1]*T) < csum[b] (per-bin, parallel,
//               closed-form over exact per-binade B segments)
//   mterm[k]  = smallest m with B[m] <= A[k]           (termination schedule)
// The serial merge is then pure integer logic, bit-identical to the reference
// trajectory.
__global__ void __launch_bounds__(256) k_search(Ws* __restrict__ ws) {
  __shared__ __align__(16) float csum[BINS];
  __shared__ float part[256];
  __shared__ __align__(16) float Atab[2052];
  __shared__ __align__(16) int   ltab[2052];
  __shared__ __align__(16) int   mterm[2052];
  __shared__ __align__(16) int   mcross[BINS];
  __shared__ float segB[NSEG], segD[NSEG];
  __shared__ int   segM[NSEG], segN[NSEG];
  __shared__ int   nseg_s, mbot_s;

  int t = threadIdx.x;

  // ---- cumsum (identical summation order to validated rounds 1-3) ----
  float loc[8];
  float s = 0.0f;
  #pragma unroll
  for (int k = 0; k < 8; ++k) {
    float h = (float)ws->hist[t * 8 + k];
    ws->histf[t * 8 + k] = h;
    s += h;
    loc[k] = s;
  }
  part[t] = s;
  __syncthreads();
  for (int off = 1; off < 256; off <<= 1) {
    float add = (t >= off) ? part[t - off] : 0.0f;
    __syncthreads();
    part[t] += add;
    __syncthreads();
  }
  float excl = (t == 0) ? 0.0f : part[t - 1];
  #pragma unroll
  for (int k = 0; k < 8; ++k) csum[t * 8 + k] = excl + loc[k];
  __syncthreads();

  const float S = STEPF;
  const float T = csum[BINS - 1];
  const float rcpT = 1.0f / T;

  // ---- thread 0: A table (exact serial fp32) + B segment table ----
  if (t == 0) {
    float a = 0.0f; Atab[0] = 0.0f;
    for (int k = 1; k < 2052; ++k) { a = a + S; Atab[k] = a; }

    int sg = 0; float B = 1.0f; int m0 = 0; int mbot = MINF;
    while (sg < NSEG && B > 0.0f) {
      float Bn = B - S;                  // one actual fp32 step
      if (Bn <= 0.0f) {
        segB[sg] = B; segD[sg] = B - Bn; segM[sg] = m0; segN[sg] = 0;
        ++sg; mbot = m0 + 1; break;
      }
      float d = B - Bn;                  // exact (Sterbenz)
      unsigned bb = __float_as_uint(B);
      unsigned bid = bb & 0x7f800000u;
      if ((bb & 0x007fffffu) == 0u) bid -= 0x00800000u;  // exact pow2 -> lower binade
      float binlo = __uint_as_float(bid);
      float brel = B - binlo;            // exact
      int n = (int)floor((double)brel / (double)d);      // exact floor (24-bit ints)
      if (n < 0) n = 0;
      if (n >= 2) {                      // guard round-to-even tie alternation
        float B1 = B - d;
        float B2 = B1 - S;               // actual second step
        if (B1 - B2 != d) n = 1;
      }
      segB[sg] = B; segD[sg] = d; segM[sg] = m0; segN[sg] = n;
      ++sg;
      float Blast = B - (float)n * d;    // exact value at index m0+n
      B = Blast - S;                     // actual boundary step -> index m0+n+1
      m0 += n + 1;
      if (B <= 0.0f) { mbot = m0; break; }
    }
    nseg_s = sg; mbot_s = mbot;
  }
  __syncthreads();

  int nsg = nseg_s;
  int mbot = mbot_s;

  // ---- parallel: ltab[k] (binary search) ----
  for (int k = t; k < 2051; k += 256) {
    float v = Atab[k + 1] * T;
    int lo = 0, hi = BINS;
    while (lo < hi) { int mid = (lo + hi) >> 1; if (csum[mid] < v) lo = mid + 1; else hi = mid; }
    ltab[k] = lo;
  }
  // ---- parallel: mterm[k] = smallest m with B[m] <= A[k] ----
  for (int k = t; k < 2052; k += 256) {
    float a = Atab[k];
    int mt = mbot;
    for (int sg = 0; sg < nsg; ++sg) {
      float Bs = segB[sg], d = segD[sg];
      int n = segN[sg], ms = segM[sg];
      float Bend = Bs - (float)n * d;
      if (Bend <= a) {
        float rd = (d > 0.0f) ? 1.0f / d : 0.0f;
        int i = (int)((Bs - a) * rd);
        if (i < 0) i = 0; if (i > n) i = n;
        while (i > 0 && Bs - (float)(i - 1) * d <= a) --i;
        while (i <= n && Bs - (float)i * d > a) ++i;
        mt = ms + i;
        break;
      }
    }
    mterm[k] = mt;
  }
  // ---- parallel: mcross[b] = smallest m with fl(B[m+1]*T) < csum[b] ----
  for (int b = t; b < BINS; b += 256) {
    float c = csum[b];
    int mc = MINF;
    if (c > 0.0f) {
      mc = (mbot == MINF) ? MINF : (mbot - 1);   // B<=0 -> product <= 0 < c
      for (int sg = 0; sg < nsg; ++sg) {
        float Bs = segB[sg], d = segD[sg];
        int n = segN[sg], ms = segM[sg];
        float Bend = Bs - (float)n * d;
        if (Bend * T < c) {
          float rd = (d > 0.0f) ? 1.0f / d : 0.0f;
          int i = (int)((Bs - c * rcpT) * rd);
          if (i < 0) i = 0; if (i > n) i = n;
          while (i > 0 && (Bs - (float)(i - 1) * d) * T < c) --i;
          while (i <= n && !((Bs - (float)i * d) * T < c)) ++i;
          int j = ms + i;                // index over B values; j = m+1
          mc = j - 1;
          break;
        }
      }
    }
    mcross[b] = mc;
  }
  __syncthreads();

  if (t != 0) return;

  // ---- serial integer merge ----
  int lb = -1024; int4 lc4 = make_int4(0, 0, 0, 0);
  int tb = -1024; int4 tc4 = make_int4(0, 0, 0, 0);
  int rb = -1024; int4 rc4 = make_int4(0, 0, 0, 0);
  int k = 0, m = 0, sb = 0, eb = BINS - 1, rptr = BINS - 1, nst = 0;
  int guard = 0;
  while (++guard < 100000) {
    if (m >= iget(mterm, tb, tc4, k)) break;              // alpha >= beta
    while (rptr >= 0 && iget(mcross, rb, rc4, rptr) <= m) --rptr;
    int l0 = iget(ltab, lb, lc4, k);
    int l = l0 < sb ? sb : (l0 > eb ? eb : l0);
    int r = rptr < sb ? sb : (rptr > eb ? eb : rptr);
    int pl = l - sb, pr = eb - r;
    if (pl > pr) {
      sb = l; ++k;
      if (nst < MAXST) ws->states[nst] = make_int2(sb, eb);
      ++nst;
      if (sb >= eb) break;
    } else if (pr > 0) {
      eb = r; ++m;
      if (nst < MAXST) ws->states[nst] = make_int2(sb, eb);
      ++nst;
      if (sb >= eb) break;
    } else {
      // no-change run: next right event at mcross[eb] (eb == rptr here),
      // termination at mterm[k]; jump to whichever comes first.
      int mx = iget(mcross, rb, rc4, eb);
      int mt = iget(mterm, tb, tc4, k);
      if (mx >= mt) break;
      m = mx;
    }
  }
  ws->n_states = (nst < MAXST) ? nst : MAXST;
}

// ---------------- Phase 3b: evaluate quantization error for all states ----------------
__global__ void __launch_bounds__(256) k_eval(Ws* __restrict__ ws) {
  int i = blockIdx.x;
  if (i >= ws->n_states) return;
  int2 st = ws->states[i];
  float bw = ws->bin_width;
  float cnt = (float)(st.y - st.x + 1);
  float w = bw * cnt / (float)DSTN;
  int t = threadIdx.x;
  if (w == 0.0f) {
    if (t == 0) ws->norms[i] = 0.0f;
    return;
  }
  float hw = 0.5f * w;
  float hw3 = hw * hw * hw;
  float nsb = (float)st.x;
  float sum = 0.0f;
  #pragma unroll
  for (int k = 0; k < 8; ++k) {
    int j = t + 256 * k;
    float h = ws->histf[j];
    float begin = ((float)j - nsb) * bw;
    float end = begin + bw;
    float db = fminf(fmaxf(floorf(begin / w), 0.0f), (float)(DSTN - 1));
    float de = fminf(fmaxf(floorf(end / w), 0.0f), (float)(DSTN - 1));
    float density = h / bw;
    float dbc = (db + 0.5f) * w;
    float a1 = begin - dbc;
    float n1 = density * (hw3 - a1 * a1 * a1) / 3.0f;
    float nmid = density * (hw3 + hw3) / 3.0f;
    float dec = de * w + hw;
    float a3 = end - dec;
    float n3 = density * (a3 * a3 * a3 + hw3) / 3.0f;
    sum += n1 + (de - db - 1.0f) * nmid + n3;
  }
  __shared__ float red[256];
  red[t] = sum;
  __syncthreads();
  for (int off = 128; off > 0; off >>= 1) {
    if (t < off) red[t] += red[t + off];
    __syncthreads();
  }
  if (t == 0) ws->norms[i] = red[0];
}

// ---------------- Phase 3c: first norm increase -> final range ----------------
__global__ void __launch_bounds__(256) k_final(Ws* __restrict__ ws, float* __restrict__ out) {
  __shared__ int sbrk[256];
  int N = ws->n_states;
  int t = threadIdx.x;
  int loc = 0x7fffffff;
  for (int i = t + 1; i < N; i += 256) {
    if (ws->norms[i] > ws->norms[i - 1]) loc = min(loc, i);
  }
  sbrk[t] = loc;
  __syncthreads();
  for (int off = 128; off > 0; off >>= 1) {
    if (t < off) sbrk[t] = min(sbrk[t], sbrk[t + off]);
    __syncthreads();
  }
  if (t == 0) {
    int sb, eb;
    if (N == 0) { sb = 0; eb = BINS - 1; }
    else {
      int ib = sbrk[0];
      int fi = (ib != 0x7fffffff) ? (ib - 1) : (N - 1);
      int2 st = ws->states[fi];
      sb = st.x; eb = st.y;
    }
    float minv = ws->min_val, bw = ws->bin_width;
    out[0] = minv + bw * (float)sb;
    out[1] = minv + bw * (float)(eb + 1);
  }
}

extern "C" void kernel_launch(void* const* d_in, const int* in_sizes, int n_in,
                              void* d_out, int out_size, void* d_ws, size_t ws_size,
                              hipStream_t stream) {
  const float* x = (const float*)d_in[0];
  long long n = (long long)in_sizes[0];
  Ws* ws = (Ws*)d_ws;
  float* out = (float*)d_out;

  k_minmax<<<NPART, 256, 0, stream>>>(x, n, ws);
  k_minmax_final<<<1, 256, 0, stream>>>(ws, NPART);
  k_hist<<<NPART, 256, 0, stream>>>(x, n, ws);
  k_search<<<1, 256, 0, stream>>>(ws);
  k_eval<<<MAXST, 256, 0, stream>>>(ws);
  k_final<<<1, 256, 0, stream>>>(ws, out);
}

// Round 5
// 410.952 us; speedup vs baseline: 3.5852x; 2.4312x over previous
//
#include <hip/hip_runtime.h>
#include <float.h>
#include <math.h>

#define BINS 2048
#define DSTN 8
#define STEPF 1e-5f
#define NPART 1024
#define MAXST 4096
#define NSEG 64
#define MINF 0x7fffffff

struct Ws {
  float pmin[NPART];
  float pmax[NPART];
  float min_val, max_val, bin_width, safe_bw;
  int   n_states;
  int   pad[3];
  unsigned int hist[BINS];
  float histf[BINS];
  float norms[MAXST];
  int2  states[MAXST];
};

// ---------------- Pass 1: block-partial min/max ----------------
__global__ void __launch_bounds__(256) k_minmax(const float* __restrict__ x, long long n,
                                                Ws* __restrict__ ws) {
  long long n4 = n >> 2;
  float vmin = FLT_MAX, vmax = -FLT_MAX;
  const float4* __restrict__ x4 = (const float4*)x;
  long long stride = (long long)gridDim.x * blockDim.x;
  for (long long i = (long long)blockIdx.x * blockDim.x + threadIdx.x; i < n4; i += stride) {
    float4 v = x4[i];
    vmin = fminf(vmin, fminf(fminf(v.x, v.y), fminf(v.z, v.w)));
    vmax = fmaxf(vmax, fmaxf(fmaxf(v.x, v.y), fmaxf(v.z, v.w)));
  }
  for (long long i = (n4 << 2) + (long long)blockIdx.x * blockDim.x + threadIdx.x; i < n; i += stride) {
    float v = x[i];
    vmin = fminf(vmin, v); vmax = fmaxf(vmax, v);
  }
  for (int off = 32; off > 0; off >>= 1) {
    vmin = fminf(vmin, __shfl_down(vmin, off));
    vmax = fmaxf(vmax, __shfl_down(vmax, off));
  }
  __shared__ float smin[4], smax[4];
  int wid = threadIdx.x >> 6;
  if ((threadIdx.x & 63) == 0) { smin[wid] = vmin; smax[wid] = vmax; }
  __syncthreads();
  if (threadIdx.x == 0) {
    float a = smin[0], b = smax[0];
    int nw = (int)(blockDim.x >> 6);
    for (int w = 1; w < nw; ++w) { a = fminf(a, smin[w]); b = fmaxf(b, smax[w]); }
    ws->pmin[blockIdx.x] = a; ws->pmax[blockIdx.x] = b;
  }
}

// ---------------- Reduce partials, compute bin_width, zero hist ----------------
__global__ void __launch_bounds__(256) k_minmax_final(Ws* __restrict__ ws, int nparts) {
  __shared__ float smin[256], smax[256];
  int t = threadIdx.x;
  float vmin = FLT_MAX, vmax = -FLT_MAX;
  for (int i = t; i < nparts; i += 256) {
    vmin = fminf(vmin, ws->pmin[i]);
    vmax = fmaxf(vmax, ws->pmax[i]);
  }
  smin[t] = vmin; smax[t] = vmax;
  __syncthreads();
  for (int off = 128; off > 0; off >>= 1) {
    if (t < off) { smin[t] = fminf(smin[t], smin[t + off]); smax[t] = fmaxf(smax[t], smax[t + off]); }
    __syncthreads();
  }
  if (t == 0) {
    float mn = smin[0], mx = smax[0];
    ws->min_val = mn; ws->max_val = mx;
    float bw = (mx - mn) / (float)BINS;
    ws->bin_width = bw;
    ws->safe_bw = (bw == 0.0f) ? 1.0f : bw;
  }
  for (int i = t; i < BINS; i += 256) ws->hist[i] = 0u;
}

// ---------------- Pass 2: histogram (LDS-private then global flush) ----------------
__global__ void __launch_bounds__(256) k_hist(const float* __restrict__ x, long long n,
                                              Ws* __restrict__ ws) {
  __shared__ unsigned int lh[BINS];
  for (int i = threadIdx.x; i < BINS; i += 256) lh[i] = 0u;
  __syncthreads();
  float minv = ws->min_val;
  float sbw = ws->safe_bw;
  long long n4 = n >> 2;
  const float4* __restrict__ x4 = (const float4*)x;
  long long stride = (long long)gridDim.x * blockDim.x;
  for (long long i = (long long)blockIdx.x * blockDim.x + threadIdx.x; i < n4; i += stride) {
    float4 v = x4[i];
    int a = (int)floorf((v.x - minv) / sbw);
    int b = (int)floorf((v.y - minv) / sbw);
    int c = (int)floorf((v.z - minv) / sbw);
    int d = (int)floorf((v.w - minv) / sbw);
    a = min(BINS - 1, max(0, a));
    b = min(BINS - 1, max(0, b));
    c = min(BINS - 1, max(0, c));
    d = min(BINS - 1, max(0, d));
    atomicAdd(&lh[a], 1u);
    atomicAdd(&lh[b], 1u);
    atomicAdd(&lh[c], 1u);
    atomicAdd(&lh[d], 1u);
  }
  for (long long i = (n4 << 2) + (long long)blockIdx.x * blockDim.x + threadIdx.x; i < n; i += stride) {
    int a = (int)floorf((x[i] - minv) / sbw);
    a = min(BINS - 1, max(0, a));
    atomicAdd(&lh[a], 1u);
  }
  __syncthreads();
  for (int i = threadIdx.x; i < BINS; i += 256) {
    unsigned int c = lh[i];
    if (c) atomicAdd(&ws->hist[i], c);
  }
}

// ---------------- Phase 3a: cumsum + fully-parallel event tables + lean merge ----
// Trajectory facts (all validated bit-exact in rounds 1-4):
//  * the (sb,eb) state list is independent of the norms (break found later);
//  * alpha sequence A[k] and beta sequence B[m] are fixed fp32 sequences;
//  * ltab[k] = searchsorted_left(csum, fl(A[k+1]*T));
//  * mcross[b] = smallest m with fl(B[m+1]*T) < csum[b]  (non-increasing in b);
//  * mterm[k] = smallest m with B[m] <= A[k].
// New this round:
//  * r(m) = largest b with mcross[b] > m, so the right-event chain from 2047
//    visits exactly the RIGHT ENDPOINTS of distinct-value runs of mcross,
//    right-to-left -> computable via parallel suffix-count + scatter.
//  * once a left gap is zero the left side is frozen forever (alpha static),
//    so left fires are a prefix of ltab; the merge is a two-list interleave:
//    lefts fire immediately while pr==0; at a coincident event time compare
//    pl > pr; all gated by m < mterm[k]. Sequential reads + rolling prefetch.
__global__ void __launch_bounds__(256) k_search(Ws* __restrict__ ws) {
  // arena: csum f32[2048] @0 | Atab f32[2052] @8192   (overlaid later by ev int2[2049] @0)
  //        ltmt int2[2052] @16400 | mcross int[2048] @32816 | chain int[2052] @41008
  __shared__ __align__(16) char arena[49216];
  float* csum   = (float*)(arena);
  float* Atab   = (float*)(arena + 8192);
  int2*  ev     = (int2*)(arena);
  int2*  ltmt   = (int2*)(arena + 16400);
  int*   mcross = (int*)(arena + 32816);
  int*   chain  = (int*)(arena + 41008);
  __shared__ float part[256];
  __shared__ int   ipart[256];
  __shared__ float segB[NSEG], segD[NSEG];
  __shared__ int   segM[NSEG], segN[NSEG];
  __shared__ int   nseg_s, mbot_s, nc_s;

  int t = threadIdx.x;

  // ---- phase 0: cumsum (identical summation order to rounds 1-4) ----
  float loc[8];
  float s = 0.0f;
  #pragma unroll
  for (int kk = 0; kk < 8; ++kk) {
    float h = (float)ws->hist[t * 8 + kk];
    ws->histf[t * 8 + kk] = h;
    s += h;
    loc[kk] = s;
  }
  part[t] = s;
  __syncthreads();
  for (int off = 1; off < 256; off <<= 1) {
    float add = (t >= off) ? part[t - off] : 0.0f;
    __syncthreads();
    part[t] += add;
    __syncthreads();
  }
  float excl = (t == 0) ? 0.0f : part[t - 1];
  #pragma unroll
  for (int kk = 0; kk < 8; ++kk) csum[t * 8 + kk] = excl + loc[kk];
  __syncthreads();

  const float S = STEPF;
  const float T = csum[BINS - 1];
  const float rcpT = 1.0f / T;

  // ---- phase 1: thread 0: exact A table + exact B binade-segment table ----
  if (t == 0) {
    float a = 0.0f; Atab[0] = 0.0f;
    for (int k = 1; k < 2052; ++k) { a = a + S; Atab[k] = a; }

    int sg = 0; float B = 1.0f; int m0 = 0; int mbot = MINF;
    while (sg < NSEG && B > 0.0f) {
      float Bn = B - S;                  // one actual fp32 step
      if (Bn <= 0.0f) {
        segB[sg] = B; segD[sg] = B - Bn; segM[sg] = m0; segN[sg] = 0;
        ++sg; mbot = m0 + 1; break;
      }
      float d = B - Bn;                  // exact (Sterbenz)
      unsigned bb = __float_as_uint(B);
      unsigned bid = bb & 0x7f800000u;
      if ((bb & 0x007fffffu) == 0u) bid -= 0x00800000u;
      float binlo = __uint_as_float(bid);
      float brel = B - binlo;            // exact
      int n = (int)floor((double)brel / (double)d);
      if (n < 0) n = 0;
      if (n >= 2) {                      // guard round-to-even tie alternation
        float B1 = B - d;
        float B2 = B1 - S;
        if (B1 - B2 != d) n = 1;
      }
      segB[sg] = B; segD[sg] = d; segM[sg] = m0; segN[sg] = n;
      ++sg;
      float Blast = B - (float)n * d;
      B = Blast - S;
      m0 += n + 1;
      if (B <= 0.0f) { mbot = m0; break; }
    }
    nseg_s = sg; mbot_s = mbot;
  }
  __syncthreads();

  int nsg = nseg_s;
  int mbot = mbot_s;

  // ---- phase 2: parallel ltab+mterm (packed) and mcross ----
  for (int k = t; k < 2052; k += 256) {
    int lo = 2048;
    if (k <= 2050) {
      float v = Atab[k + 1] * T;
      lo = 0; int hi = BINS;
      while (lo < hi) { int mid = (lo + hi) >> 1; if (csum[mid] < v) lo = mid + 1; else hi = mid; }
    }
    float a = Atab[k];
    int mt = mbot;
    for (int sg = 0; sg < nsg; ++sg) {
      float Bs = segB[sg], d = segD[sg];
      int n = segN[sg], ms = segM[sg];
      float Bend = Bs - (float)n * d;
      if (Bend <= a) {
        float rd = (d > 0.0f) ? 1.0f / d : 0.0f;
        int i = (int)((Bs - a) * rd);
        if (i < 0) i = 0; if (i > n) i = n;
        while (i > 0 && Bs - (float)(i - 1) * d <= a) --i;
        while (i <= n && Bs - (float)i * d > a) ++i;
        mt = ms + i;
        break;
      }
    }
    ltmt[k] = make_int2(lo, mt);
  }
  for (int b = t; b < BINS; b += 256) {
    float c = csum[b];
    int mc = MINF;
    if (c > 0.0f) {
      mc = (mbot == MINF) ? MINF : (mbot - 1);
      for (int sg = 0; sg < nsg; ++sg) {
        float Bs = segB[sg], d = segD[sg];
        int n = segN[sg], ms = segM[sg];
        float Bend = Bs - (float)n * d;
        if (Bend * T < c) {
          float rd = (d > 0.0f) ? 1.0f / d : 0.0f;
          int i = (int)((Bs - c * rcpT) * rd);
          if (i < 0) i = 0; if (i > n) i = n;
          while (i > 0 && (Bs - (float)(i - 1) * d) * T < c) --i;
          while (i <= n && !((Bs - (float)i * d) * T < c)) ++i;
          mc = ms + i - 1;
          break;
        }
      }
    }
    mcross[b] = mc;
  }
  __syncthreads();

  // ---- phase 3: run-endpoint ranks (suffix count) + scatter chain ----
  int mcl[8];
  int iem = 0;   // bitmask of is_end for this thread's 8 bins
  {
    int b0 = t * 8;
    #pragma unroll
    for (int kk = 0; kk < 8; ++kk) mcl[kk] = mcross[b0 + kk];
    int mnext = (t < 255) ? mcross[b0 + 8] : 0;
    int cnt = 0;
    #pragma unroll
    for (int kk = 0; kk < 8; ++kk) {
      int nxtv = (kk < 7) ? mcl[kk + 1] : mnext;
      bool e = (b0 + kk == BINS - 1) || (mcl[kk] != nxtv);
      iem |= e ? (1 << kk) : 0;
      cnt += e ? 1 : 0;
    }
    ipart[t] = cnt;
  }
  __syncthreads();
  for (int off = 1; off < 256; off <<= 1) {
    int v = (t + off < 256) ? ipart[t + off] : 0;
    __syncthreads();
    ipart[t] += v;
    __syncthreads();
  }
  {
    int running = (t < 255) ? ipart[t + 1] : 0;
    #pragma unroll
    for (int kk = 7; kk >= 0; --kk) {
      if (iem & (1 << kk)) { ++running; chain[running - 1] = t * 8 + kk; }
    }
    if (t == 0) nc_s = ipart[0];
  }
  __syncthreads();

  // ---- phase 4: parallel event list (overlays csum/Atab — both dead now) ----
  int NC = nc_s;
  for (int j = 1 + t; j <= NC; j += 256) {
    int prev = chain[j - 1];
    int mcp = mcross[prev];
    int nxt = (j < NC) ? chain[j] : -1;
    ev[j] = make_int2(mcp, nxt);
  }
  __syncthreads();

  if (t != 0) return;

  // ---- phase 5: lean serial merge (sequential reads + 3-deep prefetch) ----
  int k = 0, sb = 0, eb = BINS - 1, m = 0, j = 1, nst = 0;
  int2 lm0 = ltmt[0], lm1 = ltmt[1], lm2 = ltmt[2];
  int2 e0 = ev[1], e1 = ev[2 <= 2048 ? 2 : 2048], e2 = ev[3 <= 2048 ? 3 : 2048];
  int guard = 0;
  while (++guard < 8192) {
    int lpos = lm0.x, mt = lm0.y;
    int mc = e0.x, ne = e0.y;
    int l = min(lpos, eb);
    int pl = l - sb;
    bool coin = (m == mc);
    int nec = max(ne, sb);
    int pr = eb - nec;
    bool fl, fr;
    if (pl > 0) {
      bool ok = (m < mt);
      fl = ok && (!coin || pl > pr);
      fr = ok && coin && pl <= pr;
    } else {
      fl = false;
      fr = (mc != MINF) && (mc < mt);
    }
    if (fl) {
      sb = l; ++k;
      if (nst < MAXST) ws->states[nst] = make_int2(sb, eb);
      ++nst;
      if (sb >= eb) break;
      lm0 = lm1; lm1 = lm2; lm2 = ltmt[min(k + 2, 2051)];
    } else if (fr) {
      eb = nec; m = mc + 1; ++j;
      if (nst < MAXST) ws->states[nst] = make_int2(sb, eb);
      ++nst;
      if (sb >= eb) break;
      e0 = e1; e1 = e2; e2 = ev[min(j + 2, 2048)];
    } else {
      break;
    }
  }
  ws->n_states = (nst < MAXST) ? nst : MAXST;
}

// ---------------- Phase 3b: evaluate quantization error for all states ----------------
__global__ void __launch_bounds__(256) k_eval(Ws* __restrict__ ws) {
  int i = blockIdx.x;
  if (i >= ws->n_states) return;
  int2 st = ws->states[i];
  float bw = ws->bin_width;
  float cnt = (float)(st.y - st.x + 1);
  float w = bw * cnt / (float)DSTN;
  int t = threadIdx.x;
  if (w == 0.0f) {
    if (t == 0) ws->norms[i] = 0.0f;
    return;
  }
  float hw = 0.5f * w;
  float hw3 = hw * hw * hw;
  float nsb = (float)st.x;
  float sum = 0.0f;
  #pragma unroll
  for (int k = 0; k < 8; ++k) {
    int j = t + 256 * k;
    float h = ws->histf[j];
    float begin = ((float)j - nsb) * bw;
    float end = begin + bw;
    float db = fminf(fmaxf(floorf(begin / w), 0.0f), (float)(DSTN - 1));
    float de = fminf(fmaxf(floorf(end / w), 0.0f), (float)(DSTN - 1));
    float density = h / bw;
    float dbc = (db + 0.5f) * w;
    float a1 = begin - dbc;
    float n1 = density * (hw3 - a1 * a1 * a1) / 3.0f;
    float nmid = density * (hw3 + hw3) / 3.0f;
    float dec = de * w + hw;
    float a3 = end - dec;
    float n3 = density * (a3 * a3 * a3 + hw3) / 3.0f;
    sum += n1 + (de - db - 1.0f) * nmid + n3;
  }
  __shared__ float red[256];
  red[t] = sum;
  __syncthreads();
  for (int off = 128; off > 0; off >>= 1) {
    if (t < off) red[t] += red[t + off];
    __syncthreads();
  }
  if (t == 0) ws->norms[i] = red[0];
}

// ---------------- Phase 3c: first norm increase -> final range ----------------
__global__ void __launch_bounds__(256) k_final(Ws* __restrict__ ws, float* __restrict__ out) {
  __shared__ int sbrk[256];
  int N = ws->n_states;
  int t = threadIdx.x;
  int loc = 0x7fffffff;
  for (int i = t + 1; i < N; i += 256) {
    if (ws->norms[i] > ws->norms[i - 1]) loc = min(loc, i);
  }
  sbrk[t] = loc;
  __syncthreads();
  for (int off = 128; off > 0; off >>= 1) {
    if (t < off) sbrk[t] = min(sbrk[t], sbrk[t + off]);
    __syncthreads();
  }
  if (t == 0) {
    int sb, eb;
    if (N == 0) { sb = 0; eb = BINS - 1; }
    else {
      int ib = sbrk[0];
      int fi = (ib != 0x7fffffff) ? (ib - 1) : (N - 1);
      int2 st = ws->states[fi];
      sb = st.x; eb = st.y;
    }
    float minv = ws->min_val, bw = ws->bin_width;
    out[0] = minv + bw * (float)sb;
    out[1] = minv + bw * (float)(eb + 1);
  }
}

extern "C" void kernel_launch(void* const* d_in, const int* in_sizes, int n_in,
                              void* d_out, int out_size, void* d_ws, size_t ws_size,
                              hipStream_t stream) {
  const float* x = (const float*)d_in[0];
  long long n = (long long)in_sizes[0];
  Ws* ws = (Ws*)d_ws;
  float* out = (float*)d_out;

  k_minmax<<<NPART, 256, 0, stream>>>(x, n, ws);
  k_minmax_final<<<1, 256, 0, stream>>>(ws, NPART);
  k_hist<<<NPART, 256, 0, stream>>>(x, n, ws);
  k_search<<<1, 256, 0, stream>>>(ws);
  k_eval<<<MAXST, 256, 0, stream>>>(ws);
  k_final<<<1, 256, 0, stream>>>(ws, out);
}

// Round 6
// 162.761 us; speedup vs baseline: 9.0521x; 2.5249x over previous
//
#include <hip/hip_runtime.h>
#include <float.h>
#include <math.h>

#define BINS 2048
#define DSTN 8
#define STEPF 1e-5f
#define NPART 1024
#define MAXST 2048
#define NSEG 64
#define MINF 0x7fffffff

struct Ws {
  float pmin[NPART];
  float pmax[NPART];
  float min_val, max_val, bin_width, safe_bw;
  int   n_states;
  int   pad[3];
  unsigned int hist[BINS];
  float histf[BINS];
  float norms[MAXST];
  int2  states[MAXST];
};

// ---------------- Pass 1: block-partial min/max ----------------
__global__ void __launch_bounds__(256) k_minmax(const float* __restrict__ x, long long n,
                                                Ws* __restrict__ ws) {
  long long n4 = n >> 2;
  float vmin = FLT_MAX, vmax = -FLT_MAX;
  const float4* __restrict__ x4 = (const float4*)x;
  long long stride = (long long)gridDim.x * blockDim.x;
  for (long long i = (long long)blockIdx.x * blockDim.x + threadIdx.x; i < n4; i += stride) {
    float4 v = x4[i];
    vmin = fminf(vmin, fminf(fminf(v.x, v.y), fminf(v.z, v.w)));
    vmax = fmaxf(vmax, fmaxf(fmaxf(v.x, v.y), fmaxf(v.z, v.w)));
  }
  for (long long i = (n4 << 2) + (long long)blockIdx.x * blockDim.x + threadIdx.x; i < n; i += stride) {
    float v = x[i];
    vmin = fminf(vmin, v); vmax = fmaxf(vmax, v);
  }
  for (int off = 32; off > 0; off >>= 1) {
    vmin = fminf(vmin, __shfl_down(vmin, off));
    vmax = fmaxf(vmax, __shfl_down(vmax, off));
  }
  __shared__ float smin[4], smax[4];
  int wid = threadIdx.x >> 6;
  if ((threadIdx.x & 63) == 0) { smin[wid] = vmin; smax[wid] = vmax; }
  __syncthreads();
  if (threadIdx.x == 0) {
    float a = smin[0], b = smax[0];
    int nw = (int)(blockDim.x >> 6);
    for (int w = 1; w < nw; ++w) { a = fminf(a, smin[w]); b = fmaxf(b, smax[w]); }
    ws->pmin[blockIdx.x] = a; ws->pmax[blockIdx.x] = b;
  }
}

// ---------------- Reduce partials, compute bin_width, zero hist ----------------
__global__ void __launch_bounds__(256) k_minmax_final(Ws* __restrict__ ws, int nparts) {
  __shared__ float smin[256], smax[256];
  int t = threadIdx.x;
  float vmin = FLT_MAX, vmax = -FLT_MAX;
  for (int i = t; i < nparts; i += 256) {
    vmin = fminf(vmin, ws->pmin[i]);
    vmax = fmaxf(vmax, ws->pmax[i]);
  }
  smin[t] = vmin; smax[t] = vmax;
  __syncthreads();
  for (int off = 128; off > 0; off >>= 1) {
    if (t < off) { smin[t] = fminf(smin[t], smin[t + off]); smax[t] = fmaxf(smax[t], smax[t + off]); }
    __syncthreads();
  }
  if (t == 0) {
    float mn = smin[0], mx = smax[0];
    ws->min_val = mn; ws->max_val = mx;
    float bw = (mx - mn) / (float)BINS;
    ws->bin_width = bw;
    ws->safe_bw = (bw == 0.0f) ? 1.0f : bw;
  }
  for (int i = t; i < BINS; i += 256) ws->hist[i] = 0u;
}

// ---------------- Pass 2: histogram (LDS-private then global flush) ----------------
__global__ void __launch_bounds__(256) k_hist(const float* __restrict__ x, long long n,
                                              Ws* __restrict__ ws) {
  __shared__ unsigned int lh[BINS];
  for (int i = threadIdx.x; i < BINS; i += 256) lh[i] = 0u;
  __syncthreads();
  float minv = ws->min_val;
  float sbw = ws->safe_bw;
  long long n4 = n >> 2;
  const float4* __restrict__ x4 = (const float4*)x;
  long long stride = (long long)gridDim.x * blockDim.x;
  for (long long i = (long long)blockIdx.x * blockDim.x + threadIdx.x; i < n4; i += stride) {
    float4 v = x4[i];
    int a = (int)floorf((v.x - minv) / sbw);
    int b = (int)floorf((v.y - minv) / sbw);
    int c = (int)floorf((v.z - minv) / sbw);
    int d = (int)floorf((v.w - minv) / sbw);
    a = min(BINS - 1, max(0, a));
    b = min(BINS - 1, max(0, b));
    c = min(BINS - 1, max(0, c));
    d = min(BINS - 1, max(0, d));
    atomicAdd(&lh[a], 1u);
    atomicAdd(&lh[b], 1u);
    atomicAdd(&lh[c], 1u);
    atomicAdd(&lh[d], 1u);
  }
  for (long long i = (n4 << 2) + (long long)blockIdx.x * blockDim.x + threadIdx.x; i < n; i += stride) {
    int a = (int)floorf((x[i] - minv) / sbw);
    a = min(BINS - 1, max(0, a));
    atomicAdd(&lh[a], 1u);
  }
  __syncthreads();
  for (int i = threadIdx.x; i < BINS; i += 256) {
    unsigned int c = lh[i];
    if (c) atomicAdd(&ws->hist[i], c);
  }
}

// ---------------- Phase 3a: cumsum + parallel tables + short zipper + parallel tail ----
// Validated facts (bit-exact through round 5):
//  * state list independent of norms; A[k]/B[m] are fixed fp32 sequences;
//  * ltab[k] = searchsorted_left(csum, fl(A[k+1]*T));
//  * mcross[b] = smallest m with fl(B[m+1]*T) < csum[b] (non-increasing in b);
//  * mterm[k] = smallest m with B[m] <= A[k];
//  * right-event chain = run endpoints of mcross, right-to-left.
// New this round:
//  * Atab built from exact per-binade segments, filled in parallel, then VERIFIED
//    in parallel against the recurrence fl(A[k]+S)==A[k+1] (serial fallback) —
//    guarantees bit-exactness.
//  * batched 9-wide binary searches (latency overlap), int4-packed B segments.
//  * once ltab[k] <= sb the left is PERMANENTLY frozen; all remaining fires are
//    consecutive chain entries -> emitted in parallel. Only the short two-sided
//    zipper stays serial; its states go to LDS and are block-copied out.
__global__ void __launch_bounds__(256) k_search(Ws* __restrict__ ws) {
  // arena: csum f32[2048] @0 | Atab f32[2052] @8192  (overlaid later by ev int2[2049] @0)
  //        ltmt int2[2052] @16400 | mcross int[2048] @32816 | chain int[2052] @41008
  __shared__ __align__(16) char arena[49216];
  float* csum   = (float*)(arena);
  float* Atab   = (float*)(arena + 8192);
  int2*  ev     = (int2*)(arena);
  int2*  ltmt   = (int2*)(arena + 16400);
  int*   mcross = (int*)(arena + 32816);
  int*   chain  = (int*)(arena + 41008);
  __shared__ __align__(16) int2 sstates[MAXST];
  __shared__ float part[256];
  __shared__ int   ipart[256];
  __shared__ int   ipart2[256];
  __shared__ __align__(16) int4 segB4[NSEG];   // {B0, d, m0, n}
  __shared__ __align__(16) int4 segA4[NSEG];   // {A0, d, k0, n}
  __shared__ int nseg_s, mbot_s, nsegA_s, nc_s;
  __shared__ int pub_mode, pub_j0, pub_sb, pub_mt, pub_nst0;

  int t = threadIdx.x;

  // ---- phase 0: cumsum (identical summation order to rounds 1-5) ----
  float loc[8];
  float s = 0.0f;
  #pragma unroll
  for (int kk = 0; kk < 8; ++kk) {
    float h = (float)ws->hist[t * 8 + kk];
    ws->histf[t * 8 + kk] = h;
    s += h;
    loc[kk] = s;
  }
  part[t] = s;
  __syncthreads();
  for (int off = 1; off < 256; off <<= 1) {
    float add = (t >= off) ? part[t - off] : 0.0f;
    __syncthreads();
    part[t] += add;
    __syncthreads();
  }
  float excl = (t == 0) ? 0.0f : part[t - 1];
  #pragma unroll
  for (int kk = 0; kk < 8; ++kk) csum[t * 8 + kk] = excl + loc[kk];
  __syncthreads();

  const float S = STEPF;
  const float T = csum[BINS - 1];
  const float rcpT = 1.0f / T;

  // ---- phase 1: thread 0: B segments (validated) + A segments ----
  if (t == 0) {
    int sg = 0; float B = 1.0f; int m0 = 0; int mbot = MINF;
    while (sg < NSEG && B > 0.0f) {
      float Bn = B - S;
      if (Bn <= 0.0f) {
        segB4[sg] = make_int4(__float_as_int(B), __float_as_int(B - Bn), m0, 0);
        ++sg; mbot = m0 + 1; break;
      }
      float d = B - Bn;                  // exact (Sterbenz)
      unsigned bb = __float_as_uint(B);
      unsigned bid = bb & 0x7f800000u;
      if ((bb & 0x007fffffu) == 0u) bid -= 0x00800000u;
      float binlo = __uint_as_float(bid);
      float brel = B - binlo;
      int n = (int)floor((double)brel / (double)d);
      if (n < 0) n = 0;
      if (n >= 2) {                      // tie-alternation guard
        float B1 = B - d;
        float B2 = B1 - S;
        if (B1 - B2 != d) n = 1;
      }
      segB4[sg] = make_int4(__float_as_int(B), __float_as_int(d), m0, n);
      ++sg;
      float Blast = B - (float)n * d;
      B = Blast - S;
      m0 += n + 1;
      if (B <= 0.0f) { mbot = m0; break; }
    }
    nseg_s = sg; mbot_s = mbot;

    // A segments: A[k0+i] = A0 + i*d exactly within a binade; boundary steps actual fp32
    int sa = 0;
    segA4[sa++] = make_int4(__float_as_int(0.0f), __float_as_int(S), 0, 0);  // {A[0]=0}
    float A0 = S; int k0 = 1;                                                 // A[1]
    while (sa < NSEG && k0 <= 2051) {
      float An = A0 + S;                 // actual step
      float d = An - A0;                 // exact (Sterbenz: A0 >= An/2)
      unsigned ab = __float_as_uint(A0);
      unsigned abid = ab & 0x7f800000u;  // binade start of A0 (ascending: no pow2 adjust)
      float binhi = __uint_as_float(abid + 0x00800000u);
      float brel = binhi - A0;           // exact
      int n = (int)floorf(brel / d);
      if (n < 0) n = 0;
      while (n >= 1 && !(A0 + (float)n * d < binhi)) --n;
      while (A0 + (float)(n + 1) * d < binhi) ++n;
      if (n >= 2) {                      // tie-alternation guard
        float A1 = A0 + d;
        float A2 = A1 + S;
        if (A2 - A1 != d) n = 1;
      }
      if (k0 + n > 2051) n = 2051 - k0;
      segA4[sa++] = make_int4(__float_as_int(A0), __float_as_int(d), k0, n);
      float Alast = A0 + (float)n * d;
      A0 = Alast + S;                    // actual boundary step
      k0 += n + 1;
    }
    nsegA_s = sa;
  }
  __syncthreads();

  int nsg = nseg_s;
  int mbot = mbot_s;
  int nsa = nsegA_s;

  // ---- phase 1b: parallel Atab fill from A segments ----
  for (int k = t; k < 2052; k += 256) {
    float val = 0.0f;
    for (int sg = 0; sg < nsa; ++sg) {
      int4 sv = segA4[sg];
      if (k <= sv.z + sv.w) { val = __int_as_float(sv.x) + (float)(k - sv.z) * __int_as_float(sv.y); break; }
    }
    Atab[k] = val;
  }
  __syncthreads();

  // ---- phase 1c: exact verification of the recurrence; serial fallback if needed ----
  {
    int okA = 1;
    for (int k = t; k < 2051; k += 256) okA &= (Atab[k] + S == Atab[k + 1]) ? 1 : 0;
    ipart[t] = okA;
    __syncthreads();
    for (int off = 128; off > 0; off >>= 1) {
      if (t < off) ipart[t] = min(ipart[t], ipart[t + off]);
      __syncthreads();
    }
    if (ipart[0] == 0) {                 // fallback: exact serial build
      if (t == 0) {
        float a = 0.0f; Atab[0] = 0.0f;
        for (int k = 1; k < 2052; ++k) { a = a + S; Atab[k] = a; }
      }
      __syncthreads();
    }
  }

  // ---- phase 2: batched ltab (9-wide, 12 guarded levels) + mterm + mcross ----
  int lov[9], hiv[9];
  float av1[9];
  #pragma unroll
  for (int i = 0; i < 9; ++i) {
    int k = t + 256 * i;
    lov[i] = 0; hiv[i] = BINS;
    av1[i] = (k <= 2050) ? Atab[k + 1] * T : FLT_MAX;
  }
  #pragma unroll
  for (int lev = 0; lev < 12; ++lev) {
    #pragma unroll
    for (int i = 0; i < 9; ++i) {
      bool act = lov[i] < hiv[i];
      int mid = act ? ((lov[i] + hiv[i]) >> 1) : 0;
      float cv = csum[mid];
      bool g = act && (cv < av1[i]);
      lov[i] = g ? (mid + 1) : lov[i];
      hiv[i] = (act && !g) ? mid : hiv[i];
    }
  }
  #pragma unroll
  for (int i = 0; i < 9; ++i) {
    int k = t + 256 * i;
    if (k >= 2052) break;
    float a = Atab[k];
    int mt = mbot;
    for (int sg = 0; sg < nsg; ++sg) {
      int4 sv = segB4[sg];
      float Bs = __int_as_float(sv.x), dd = __int_as_float(sv.y);
      int ms = sv.z, n = sv.w;
      float Bend = Bs - (float)n * dd;
      if (Bend <= a) {
        float rd = (dd > 0.0f) ? 1.0f / dd : 0.0f;
        int i2 = (int)((Bs - a) * rd);
        if (i2 < 0) i2 = 0; if (i2 > n) i2 = n;
        while (i2 > 0 && Bs - (float)(i2 - 1) * dd <= a) --i2;
        while (i2 <= n && Bs - (float)i2 * dd > a) ++i2;
        mt = ms + i2;
        break;
      }
    }
    ltmt[k] = make_int2(lov[i], mt);
  }
  for (int b = t; b < BINS; b += 256) {
    float c = csum[b];
    int mc = MINF;
    if (c > 0.0f) {
      mc = (mbot == MINF) ? MINF : (mbot - 1);
      for (int sg = 0; sg < nsg; ++sg) {
        int4 sv = segB4[sg];
        float Bs = __int_as_float(sv.x), dd = __int_as_float(sv.y);
        int ms = sv.z, n = sv.w;
        float Bend = Bs - (float)n * dd;
        if (Bend * T < c) {
          float rd = (dd > 0.0f) ? 1.0f / dd : 0.0f;
          int i2 = (int)((Bs - c * rcpT) * rd);
          if (i2 < 0) i2 = 0; if (i2 > n) i2 = n;
          while (i2 > 0 && (Bs - (float)(i2 - 1) * dd) * T < c) --i2;
          while (i2 <= n && !((Bs - (float)i2 * dd) * T < c)) ++i2;
          mc = ms + i2 - 1;
          break;
        }
      }
    }
    mcross[b] = mc;
  }
  __syncthreads();

  // ---- phase 3: run-endpoint ranks (suffix count) + scatter chain ----
  int mcl[8];
  int iem = 0;
  {
    int b0 = t * 8;
    #pragma unroll
    for (int kk = 0; kk < 8; ++kk) mcl[kk] = mcross[b0 + kk];
    int mnext = (t < 255) ? mcross[b0 + 8] : 0;
    int cnt = 0;
    #pragma unroll
    for (int kk = 0; kk < 8; ++kk) {
      int nxtv = (kk < 7) ? mcl[kk + 1] : mnext;
      bool e = (b0 + kk == BINS - 1) || (mcl[kk] != nxtv);
      iem |= e ? (1 << kk) : 0;
      cnt += e ? 1 : 0;
    }
    ipart[t] = cnt;
  }
  __syncthreads();
  for (int off = 1; off < 256; off <<= 1) {
    int v = (t + off < 256) ? ipart[t + off] : 0;
    __syncthreads();
    ipart[t] += v;
    __syncthreads();
  }
  {
    int running = (t < 255) ? ipart[t + 1] : 0;
    #pragma unroll
    for (int kk = 7; kk >= 0; --kk) {
      if (iem & (1 << kk)) { ++running; chain[running - 1] = t * 8 + kk; }
    }
    if (t == 0) nc_s = ipart[0];
  }
  __syncthreads();

  // ---- phase 4: parallel event list (overlays csum/Atab — both dead now) ----
  int NC = nc_s;
  for (int j = 1 + t; j <= NC; j += 256) {
    int prev = chain[j - 1];
    int mcp = mcross[prev];
    int nxt = (j < NC) ? chain[j] : -1;
    ev[j] = make_int2(mcp, nxt);
  }
  __syncthreads();

  // ---- phase 5: short serial zipper (thread 0), states to LDS ----
  if (t == 0) {
    int k = 0, sb = 0, eb = BINS - 1, m = 0, j = 1, nst = 0;
    int2 lm0 = ltmt[0], lm1 = ltmt[1], lm2 = ltmt[2];
    int2 e0 = ev[1], e1 = ev[2], e2 = ev[3];
    int mode = 0;
    int guard = 0;
    while (++guard < 6000) {
      int lpos = lm0.x, mt = lm0.y;
      int mc = e0.x, ne = e0.y;
      int l = min(lpos, eb);
      int pl = l - sb;
      if (pl <= 0) { mode = 1; pub_j0 = j; pub_sb = sb; pub_mt = mt; break; }  // left frozen forever
      if (m >= mt) break;                               // alpha >= beta
      bool coin = (m == mc);
      int nec = max(ne, sb);
      int pr = eb - nec;
      bool fl = !coin || (pl > pr);
      if (fl) {
        sb = l; ++k;
        sstates[nst] = make_int2(sb, eb); ++nst;
        if (sb >= eb) break;
        lm0 = lm1; lm1 = lm2; lm2 = ltmt[min(k + 2, 2051)];
      } else {
        eb = nec; m = mc + 1; ++j;
        sstates[nst] = make_int2(sb, eb); ++nst;
        if (sb >= eb) break;
        e0 = e1; e1 = e2; e2 = ev[min(j + 2, 2048)];
      }
    }
    pub_mode = mode; pub_nst0 = nst;
    if (mode == 0) { pub_j0 = 0; pub_sb = 0; pub_mt = 0; }
  }
  __syncthreads();

  // ---- phase 6: parallel tail emission + copies ----
  int mode = pub_mode;
  int nst0 = pub_nst0;
  int ntot = nst0;
  if (mode == 1) {
    int j0 = pub_j0, sbF = pub_sb, mtF = pub_mt;
    int locA = NC + 1, locB = NC + 1;
    for (int j = j0 + t; j <= NC; j += 256) {
      int2 e = ev[j];
      if (e.x >= mtF && j < locA) locA = j;   // includes MINF
      if (e.y <= sbF && j < locB) locB = j;
    }
    ipart[t] = locA; ipart2[t] = locB;
    __syncthreads();
    for (int off = 128; off > 0; off >>= 1) {
      if (t < off) {
        ipart[t] = min(ipart[t], ipart[t + off]);
        ipart2[t] = min(ipart2[t], ipart2[t + off]);
      }
      __syncthreads();
    }
    int jA = ipart[0], jB = ipart2[0];
    int nfire, clampLast;
    if (jB < jA) { nfire = jB - j0 + 1; clampLast = 1; }
    else         { nfire = jA - j0;     clampLast = 0; }
    if (nfire < 0) nfire = 0;
    ntot = nst0 + nfire;
    if (ntot > MAXST) ntot = MAXST;
    for (int i = t; i < nfire; i += 256) {
      int idx = nst0 + i;
      if (idx < MAXST) {
        int y = ev[j0 + i].y;
        int ebv = (clampLast && i == nfire - 1) ? sbF : y;
        ws->states[idx] = make_int2(sbF, ebv);
      }
    }
  }
  for (int i = t; i < nst0 && i < MAXST; i += 256) ws->states[i] = sstates[i];
  if (t == 0) ws->n_states = ntot;
}

// ---------------- Phase 3b: evaluate quantization error for all states ----------------
__global__ void __launch_bounds__(256) k_eval(Ws* __restrict__ ws) {
  int i = blockIdx.x;
  if (i >= ws->n_states) return;
  int2 st = ws->states[i];
  float bw = ws->bin_width;
  float cnt = (float)(st.y - st.x + 1);
  float w = bw * cnt / (float)DSTN;
  int t = threadIdx.x;
  if (w == 0.0f) {
    if (t == 0) ws->norms[i] = 0.0f;
    return;
  }
  float hw = 0.5f * w;
  float hw3 = hw * hw * hw;
  float nsb = (float)st.x;
  float sum = 0.0f;
  #pragma unroll
  for (int k = 0; k < 8; ++k) {
    int j = t + 256 * k;
    float h = ws->histf[j];
    float begin = ((float)j - nsb) * bw;
    float end = begin + bw;
    float db = fminf(fmaxf(floorf(begin / w), 0.0f), (float)(DSTN - 1));
    float de = fminf(fmaxf(floorf(end / w), 0.0f), (float)(DSTN - 1));
    float density = h / bw;
    float dbc = (db + 0.5f) * w;
    float a1 = begin - dbc;
    float n1 = density * (hw3 - a1 * a1 * a1) / 3.0f;
    float nmid = density * (hw3 + hw3) / 3.0f;
    float dec = de * w + hw;
    float a3 = end - dec;
    float n3 = density * (a3 * a3 * a3 + hw3) / 3.0f;
    sum += n1 + (de - db - 1.0f) * nmid + n3;
  }
  __shared__ float red[256];
  red[t] = sum;
  __syncthreads();
  for (int off = 128; off > 0; off >>= 1) {
    if (t < off) red[t] += red[t + off];
    __syncthreads();
  }
  if (t == 0) ws->norms[i] = red[0];
}

// ---------------- Phase 3c: first norm increase -> final range ----------------
__global__ void __launch_bounds__(256) k_final(Ws* __restrict__ ws, float* __restrict__ out) {
  __shared__ int sbrk[256];
  int N = ws->n_states;
  int t = threadIdx.x;
  int loc = 0x7fffffff;
  for (int i = t + 1; i < N; i += 256) {
    if (ws->norms[i] > ws->norms[i - 1]) loc = min(loc, i);
  }
  sbrk[t] = loc;
  __syncthreads();
  for (int off = 128; off > 0; off >>= 1) {
    if (t < off) sbrk[t] = min(sbrk[t], sbrk[t + off]);
    __syncthreads();
  }
  if (t == 0) {
    int sb, eb;
    if (N == 0) { sb = 0; eb = BINS - 1; }
    else {
      int ib = sbrk[0];
      int fi = (ib != 0x7fffffff) ? (ib - 1) : (N - 1);
      int2 st = ws->states[fi];
      sb = st.x; eb = st.y;
    }
    float minv = ws->min_val, bw = ws->bin_width;
    out[0] = minv + bw * (float)sb;
    out[1] = minv + bw * (float)(eb + 1);
  }
}

extern "C" void kernel_launch(void* const* d_in, const int* in_sizes, int n_in,
                              void* d_out, int out_size, void* d_ws, size_t ws_size,
                              hipStream_t stream) {
  const float* x = (const float*)d_in[0];
  long long n = (long long)in_sizes[0];
  Ws* ws = (Ws*)d_ws;
  float* out = (float*)d_out;

  k_minmax<<<NPART, 256, 0, stream>>>(x, n, ws);
  k_minmax_final<<<1, 256, 0, stream>>>(ws, NPART);
  k_hist<<<NPART, 256, 0, stream>>>(x, n, ws);
  k_search<<<1, 256, 0, stream>>>(ws);
  k_eval<<<MAXST, 256, 0, stream>>>(ws);
  k_final<<<1, 256, 0, stream>>>(ws, out);
}

// Round 7
// 155.321 us; speedup vs baseline: 9.4857x; 1.0479x over previous
//
#include <hip/hip_runtime.h>
#include <float.h>
#include <math.h>

#define BINS 2048
#define DSTN 8
#define STEPF 1e-5f
#define NPART 1024
#define MAXST 2048
#define NSEG 64
#define MINF 0x7fffffff
#define NT 512

struct Ws {
  float pmin[NPART];
  float pmax[NPART];
  float min_val, max_val, bin_width, safe_bw;
  int   n_states;
  int   pad[3];
  unsigned int hist[BINS];
  float histf[BINS];
  float norms[MAXST];
  int2  states[MAXST];
};

// ---------------- Pass 1: block-partial min/max ----------------
__global__ void __launch_bounds__(256) k_minmax(const float* __restrict__ x, long long n,
                                                Ws* __restrict__ ws) {
  long long n4 = n >> 2;
  float vmin = FLT_MAX, vmax = -FLT_MAX;
  const float4* __restrict__ x4 = (const float4*)x;
  long long stride = (long long)gridDim.x * blockDim.x;
  for (long long i = (long long)blockIdx.x * blockDim.x + threadIdx.x; i < n4; i += stride) {
    float4 v = x4[i];
    vmin = fminf(vmin, fminf(fminf(v.x, v.y), fminf(v.z, v.w)));
    vmax = fmaxf(vmax, fmaxf(fmaxf(v.x, v.y), fmaxf(v.z, v.w)));
  }
  for (long long i = (n4 << 2) + (long long)blockIdx.x * blockDim.x + threadIdx.x; i < n; i += stride) {
    float v = x[i];
    vmin = fminf(vmin, v); vmax = fmaxf(vmax, v);
  }
  for (int off = 32; off > 0; off >>= 1) {
    vmin = fminf(vmin, __shfl_down(vmin, off));
    vmax = fmaxf(vmax, __shfl_down(vmax, off));
  }
  __shared__ float smin[4], smax[4];
  int wid = threadIdx.x >> 6;
  if ((threadIdx.x & 63) == 0) { smin[wid] = vmin; smax[wid] = vmax; }
  __syncthreads();
  if (threadIdx.x == 0) {
    float a = smin[0], b = smax[0];
    int nw = (int)(blockDim.x >> 6);
    for (int w = 1; w < nw; ++w) { a = fminf(a, smin[w]); b = fmaxf(b, smax[w]); }
    ws->pmin[blockIdx.x] = a; ws->pmax[blockIdx.x] = b;
  }
}

// ---------------- Reduce partials, compute bin_width, zero hist ----------------
__global__ void __launch_bounds__(256) k_minmax_final(Ws* __restrict__ ws, int nparts) {
  __shared__ float smin[256], smax[256];
  int t = threadIdx.x;
  float vmin = FLT_MAX, vmax = -FLT_MAX;
  for (int i = t; i < nparts; i += 256) {
    vmin = fminf(vmin, ws->pmin[i]);
    vmax = fmaxf(vmax, ws->pmax[i]);
  }
  smin[t] = vmin; smax[t] = vmax;
  __syncthreads();
  for (int off = 128; off > 0; off >>= 1) {
    if (t < off) { smin[t] = fminf(smin[t], smin[t + off]); smax[t] = fmaxf(smax[t], smax[t + off]); }
    __syncthreads();
  }
  if (t == 0) {
    float mn = smin[0], mx = smax[0];
    ws->min_val = mn; ws->max_val = mx;
    float bw = (mx - mn) / (float)BINS;
    ws->bin_width = bw;
    ws->safe_bw = (bw == 0.0f) ? 1.0f : bw;
  }
  for (int i = t; i < BINS; i += 256) ws->hist[i] = 0u;
}

// ---------------- Pass 2: histogram, 4-way LDS sub-hists to cut same-bin contention ----
__global__ void __launch_bounds__(256) k_hist(const float* __restrict__ x, long long n,
                                              Ws* __restrict__ ws) {
  __shared__ __align__(16) unsigned int lh[BINS * 4];
  for (int i = threadIdx.x; i < BINS * 4; i += 256) lh[i] = 0u;
  __syncthreads();
  float minv = ws->min_val;
  float sbw = ws->safe_bw;
  int sub = threadIdx.x & 3;
  long long n4 = n >> 2;
  const float4* __restrict__ x4 = (const float4*)x;
  long long stride = (long long)gridDim.x * blockDim.x;
  for (long long i = (long long)blockIdx.x * blockDim.x + threadIdx.x; i < n4; i += stride) {
    float4 v = x4[i];
    int a = (int)floorf((v.x - minv) / sbw);
    int b = (int)floorf((v.y - minv) / sbw);
    int c = (int)floorf((v.z - minv) / sbw);
    int d = (int)floorf((v.w - minv) / sbw);
    a = min(BINS - 1, max(0, a));
    b = min(BINS - 1, max(0, b));
    c = min(BINS - 1, max(0, c));
    d = min(BINS - 1, max(0, d));
    atomicAdd(&lh[(a << 2) | sub], 1u);
    atomicAdd(&lh[(b << 2) | sub], 1u);
    atomicAdd(&lh[(c << 2) | sub], 1u);
    atomicAdd(&lh[(d << 2) | sub], 1u);
  }
  for (long long i = (n4 << 2) + (long long)blockIdx.x * blockDim.x + threadIdx.x; i < n; i += stride) {
    int a = (int)floorf((x[i] - minv) / sbw);
    a = min(BINS - 1, max(0, a));
    atomicAdd(&lh[(a << 2) | sub], 1u);
  }
  __syncthreads();
  for (int i = threadIdx.x; i < BINS; i += 256) {
    uint4 v = *((const uint4*)lh + i);
    unsigned int c = v.x + v.y + v.z + v.w;
    if (c) atomicAdd(&ws->hist[i], c);
  }
}

// ---------------- Phase 3a: cumsum + parallel tables (range-inverted) + zipper + tail ----
// Validated facts (bit-exact through round 6):
//  * state list independent of norms; A[k]/B[m] fixed fp32 sequences;
//  * ltab[k] = searchsorted_left(csum, fl(A[k+1]*T));
//  * mcross[b] = smallest m with fl(B[m+1]*T) < csum[b] (non-increasing in b);
//  * mterm[k] = smallest m with B[m] <= A[k]; right chain = run endpoints of mcross.
// New this round:
//  * all counts are integers < 2^25 (N = 2^25) so every partial sum is fp32-exact
//    regardless of association -> wave-shuffle scans replace Hillis-Steele;
//  * mterm/mcross/Atab computed by RANGE INVERSION: Atab ascending + Bend_s
//    descending make each segment's query set a contiguous range; ~18 parallel
//    binary searches give the bounds, then outer-serial x inner-parallel fills
//    (kills the per-item dependent segment scans);
//  * NT=512 (2 waves/SIMD) for latency hiding in parallel phases.
__global__ void __launch_bounds__(NT) k_search(Ws* __restrict__ ws) {
  // arena: csum f32[2048] @0 | Atab f32[2052] @8192  (overlaid later by ev int2[0..2048] @0)
  //        ltmt int2[2052] @16400 | mcross int[2048] @32816 | chain int[2052] @41008
  __shared__ __align__(16) char arena[49216];
  float* csum   = (float*)(arena);
  float* Atab   = (float*)(arena + 8192);
  int2*  ev     = (int2*)(arena);
  int2*  ltmt   = (int2*)(arena + 16400);
  int*   mcross = (int*)(arena + 32816);
  int*   chain  = (int*)(arena + 41008);
  __shared__ __align__(16) int2 sstates[MAXST];
  __shared__ float fred[8];
  __shared__ int   ired[8], ired2[8];
  __shared__ __align__(16) int4 segB4[NSEG];   // {B0, d, m0, n}
  __shared__ __align__(16) int4 segA4[NSEG];   // {A0, d, k0, n}
  __shared__ int segklo[NSEG], segblo[NSEG];
  __shared__ int nseg_s, mbot_s, nsegA_s, nc_s;
  __shared__ int pub_mode, pub_j0, pub_sb, pub_mt, pub_nst0, pub_nfire, pub_clamp, pub_ntot;

  int t = threadIdx.x;
  int lane = t & 63, wid = t >> 6;
  const float S = STEPF;

  // ---- phase 0: cumsum (integer-exact under any association) ----
  float loc[4];
  float s = 0.0f;
  #pragma unroll
  for (int kk = 0; kk < 4; ++kk) {
    float h = (float)ws->hist[t * 4 + kk];
    ws->histf[t * 4 + kk] = h;
    s += h;
    loc[kk] = s;
  }
  float isc = s;
  #pragma unroll
  for (int off = 1; off < 64; off <<= 1) {
    float u = __shfl_up(isc, off);
    if (lane >= off) isc += u;
  }
  if (lane == 63) fred[wid] = isc;
  __syncthreads();
  if (t < 8) {
    float v = fred[t];
    #pragma unroll
    for (int off = 1; off < 8; off <<= 1) {
      float u = __shfl_up(v, off, 8);
      if ((t & 7) >= off) v += u;
    }
    fred[t] = v;
  }
  __syncthreads();
  {
    float base = wid ? fred[wid - 1] : 0.0f;
    float excl = base + (isc - s);
    #pragma unroll
    for (int kk = 0; kk < 4; ++kk) csum[t * 4 + kk] = excl + loc[kk];
  }
  __syncthreads();

  const float T = csum[BINS - 1];
  const float rcpT = 1.0f / T;

  // ---- phase 1: thread 0: exact B and A binade-segment tables (data-independent) ----
  if (t == 0) {
    int sg = 0; float B = 1.0f; int m0 = 0; int mbot = MINF;
    while (sg < NSEG && B > 0.0f) {
      float Bn = B - S;
      if (Bn <= 0.0f) {
        segB4[sg] = make_int4(__float_as_int(B), __float_as_int(B - Bn), m0, 0);
        ++sg; mbot = m0 + 1; break;
      }
      float d = B - Bn;                  // exact (Sterbenz)
      unsigned bb = __float_as_uint(B);
      unsigned bid = bb & 0x7f800000u;
      if ((bb & 0x007fffffu) == 0u) bid -= 0x00800000u;
      float binlo = __uint_as_float(bid);
      float brel = B - binlo;
      int n = (int)floor((double)brel / (double)d);
      if (n < 0) n = 0;
      if (n >= 2) {                      // tie-alternation guard
        float B1 = B - d;
        float B2 = B1 - S;
        if (B1 - B2 != d) n = 1;
      }
      segB4[sg] = make_int4(__float_as_int(B), __float_as_int(d), m0, n);
      ++sg;
      float Blast = B - (float)n * d;
      B = Blast - S;
      m0 += n + 1;
      if (B <= 0.0f) { mbot = m0; break; }
    }
    nseg_s = sg; mbot_s = mbot;

    int sa = 0;
    segA4[sa++] = make_int4(__float_as_int(0.0f), __float_as_int(S), 0, 0);  // A[0]=0
    float A0 = S; int k0 = 1;
    while (sa < NSEG && k0 <= 2051) {
      float An = A0 + S;
      float d = An - A0;                 // exact
      unsigned ab = __float_as_uint(A0);
      unsigned abid = ab & 0x7f800000u;
      float binhi = __uint_as_float(abid + 0x00800000u);
      float brel = binhi - A0;
      int n = (int)floorf(brel / d);
      if (n < 0) n = 0;
      while (n >= 1 && !(A0 + (float)n * d < binhi)) --n;
      while (A0 + (float)(n + 1) * d < binhi) ++n;
      if (n >= 2) {                      // tie-alternation guard
        float A1 = A0 + d;
        float A2 = A1 + S;
        if (A2 - A1 != d) n = 1;
      }
      if (k0 + n > 2051) n = 2051 - k0;
      segA4[sa++] = make_int4(__float_as_int(A0), __float_as_int(d), k0, n);
      float Alast = A0 + (float)n * d;
      A0 = Alast + S;
      k0 += n + 1;
    }
    nsegA_s = sa;
  }
  __syncthreads();

  int nsg = nseg_s;
  int mbot = mbot_s;
  int nsa = nsegA_s;

  // ---- phase 1b: Atab fill, per-segment outer-serial x inner-parallel ----
  for (int sg = 0; sg < nsa; ++sg) {
    int4 sv = segA4[sg];
    float A0v = __int_as_float(sv.x), dv = __int_as_float(sv.y);
    for (int i = t; i <= sv.w; i += NT) Atab[sv.z + i] = A0v + (float)i * dv;
  }
  __syncthreads();

  // ---- phase 1c: exact recurrence verification; serial fallback if needed ----
  {
    int okA = 1;
    for (int k = t; k < 2051; k += NT) okA &= (Atab[k] + S == Atab[k + 1]) ? 1 : 0;
    if (__syncthreads_and(okA) == 0) {
      if (t == 0) {
        float a = 0.0f; Atab[0] = 0.0f;
        for (int k = 1; k < 2052; ++k) { a = a + S; Atab[k] = a; }
      }
      __syncthreads();
    }
  }

  // ---- phase 2a: batched ltab binary searches (5-wide, 12 guarded levels) ----
  {
    int lov[5], hiv[5];
    float av1[5];
    #pragma unroll
    for (int i = 0; i < 5; ++i) {
      int k = t + NT * i;
      lov[i] = 0; hiv[i] = BINS;
      av1[i] = (k <= 2050) ? Atab[k + 1] * T : FLT_MAX;
    }
    #pragma unroll
    for (int lev = 0; lev < 12; ++lev) {
      #pragma unroll
      for (int i = 0; i < 5; ++i) {
        bool act = lov[i] < hiv[i];
        int mid = act ? ((lov[i] + hiv[i]) >> 1) : 0;
        float cv = csum[mid];
        bool g = act && (cv < av1[i]);
        lov[i] = g ? (mid + 1) : lov[i];
        hiv[i] = (act && !g) ? mid : hiv[i];
      }
    }
    #pragma unroll
    for (int i = 0; i < 5; ++i) {
      int k = t + NT * i;
      if (k < 2052) ltmt[k] = make_int2((k <= 2050) ? lov[i] : BINS, 0);
    }
  }
  // ---- per-segment range bounds (18 independent binary searches) ----
  if (t < nsg) {
    int4 sv = segB4[t];
    float Bs = __int_as_float(sv.x), dd = __int_as_float(sv.y);
    float Bend = Bs - (float)sv.w * dd;
    int lo = 0, hi = 2052;                       // klo: first k with Atab[k] >= Bend
    while (lo < hi) { int mid = (lo + hi) >> 1; if (Atab[mid] < Bend) lo = mid + 1; else hi = mid; }
    segklo[t] = lo;
    float vt = Bend * T;                         // blo: first b with csum[b] > Bend*T
    lo = 0; hi = BINS;
    while (lo < hi) { int mid = (lo + hi) >> 1; if (!(csum[mid] > vt)) lo = mid + 1; else hi = mid; }
    segblo[t] = lo;
  }
  __syncthreads();

  // ---- phase 2b: mterm via range inversion (writes ltmt[k].y) ----
  {
    int* ltY = (int*)ltmt;
    for (int sg = 0; sg < nsg; ++sg) {
      int lo = segklo[sg], hi = (sg ? segklo[sg - 1] : 2052);
      if (lo >= hi) continue;
      int4 sv = segB4[sg];
      float Bs = __int_as_float(sv.x), dd = __int_as_float(sv.y);
      int ms = sv.z, n = sv.w;
      float rd = (dd > 0.0f) ? 1.0f / dd : 0.0f;
      for (int k = lo + t; k < hi; k += NT) {
        float a = Atab[k];
        int i2 = (int)((Bs - a) * rd);
        if (i2 < 0) i2 = 0; if (i2 > n) i2 = n;
        while (i2 > 0 && Bs - (float)(i2 - 1) * dd <= a) --i2;
        while (i2 <= n && Bs - (float)i2 * dd > a) ++i2;
        ltY[2 * k + 1] = ms + i2;
      }
    }
    int dhi = segklo[nsg - 1];
    for (int k = t; k < dhi; k += NT) ltY[2 * k + 1] = mbot;
  }
  // ---- phase 2c: mcross via range inversion ----
  {
    for (int sg = 0; sg < nsg; ++sg) {
      int lo = segblo[sg], hi = (sg ? segblo[sg - 1] : BINS);
      if (lo >= hi) continue;
      int4 sv = segB4[sg];
      float Bs = __int_as_float(sv.x), dd = __int_as_float(sv.y);
      int ms = sv.z, n = sv.w;
      float rd = (dd > 0.0f) ? 1.0f / dd : 0.0f;
      for (int b = lo + t; b < hi; b += NT) {
        float c = csum[b];
        int i2 = (int)((Bs - c * rcpT) * rd);
        if (i2 < 0) i2 = 0; if (i2 > n) i2 = n;
        while (i2 > 0 && (Bs - (float)(i2 - 1) * dd) * T < c) --i2;
        while (i2 <= n && !((Bs - (float)i2 * dd) * T < c)) ++i2;
        mcross[b] = ms + i2 - 1;
      }
    }
    int dhi = segblo[nsg - 1];
    for (int b = t; b < dhi; b += NT) {
      float c = csum[b];
      mcross[b] = (c > 0.0f) ? ((mbot == MINF) ? MINF : (mbot - 1)) : MINF;
    }
  }
  __syncthreads();

  // ---- phase 3: run-endpoint ranks (wave-scan suffix count) + scatter chain ----
  int iem = 0, cnt = 0;
  {
    int b0 = t * 4;
    int mcl[4];
    #pragma unroll
    for (int kk = 0; kk < 4; ++kk) mcl[kk] = mcross[b0 + kk];
    int mnext = (t < NT - 1) ? mcross[b0 + 4] : 0;
    #pragma unroll
    for (int kk = 0; kk < 4; ++kk) {
      int nxtv = (kk < 3) ? mcl[kk + 1] : mnext;
      bool e = (b0 + kk == BINS - 1) || (mcl[kk] != nxtv);
      iem |= e ? (1 << kk) : 0;
      cnt += e ? 1 : 0;
    }
  }
  {
    int inc = cnt;
    #pragma unroll
    for (int off = 1; off < 64; off <<= 1) {
      int u = __shfl_up(inc, off);
      if (lane >= off) inc += u;
    }
    if (lane == 63) ired[wid] = inc;
    __syncthreads();
    if (t < 8) {
      int v = ired[t];
      #pragma unroll
      for (int off = 1; off < 8; off <<= 1) {
        int u = __shfl_up(v, off, 8);
        if ((t & 7) >= off) v += u;
      }
      ired[t] = v;
    }
    __syncthreads();
    int base = wid ? ired[wid - 1] : 0;
    int incl_t = base + inc;
    int total = ired[7];
    int running = total - incl_t;
    #pragma unroll
    for (int kk = 3; kk >= 0; --kk) {
      if (iem & (1 << kk)) { ++running; chain[running - 1] = t * 4 + kk; }
    }
    if (t == 0) nc_s = total;
  }
  __syncthreads();

  // ---- phase 4: parallel event list (overlays csum/Atab — both dead now) ----
  int NC = nc_s;
  for (int j = 1 + t; j <= NC; j += NT) {
    int prev = chain[j - 1];
    ev[j] = make_int2(mcross[prev], (j < NC) ? chain[j] : -1);
  }
  if (t == 0 && NC < 2048) ev[NC + 1] = make_int2(MINF, -1);
  __syncthreads();

  // ---- phase 5: short serial zipper (thread 0), states to LDS ----
  if (t == 0) {
    int k = 0, sb = 0, eb = BINS - 1, m = 0, j = 1, nst = 0;
    int2 lm0 = ltmt[0], lm1 = ltmt[1], lm2 = ltmt[2];
    int2 e0 = ev[1], e1 = ev[2], e2 = ev[3];
    int mode = 0;
    int guard = 0;
    pub_j0 = 0; pub_sb = 0; pub_mt = 0;
    while (++guard < 6000) {
      int lpos = lm0.x, mt = lm0.y;
      int mc = e0.x, ne = e0.y;
      int l = min(lpos, eb);
      int pl = l - sb;
      if (pl <= 0) { mode = 1; pub_j0 = j; pub_sb = sb; pub_mt = mt; break; }  // left frozen forever
      if (m >= mt) break;                               // alpha >= beta
      bool coin = (m == mc);
      int nec = max(ne, sb);
      int pr = eb - nec;
      bool fl = !coin || (pl > pr);
      if (fl) {
        sb = l; ++k;
        if (nst < MAXST) sstates[nst] = make_int2(sb, eb);
        ++nst;
        if (sb >= eb) break;
        lm0 = lm1; lm1 = lm2; lm2 = ltmt[min(k + 2, 2051)];
      } else {
        eb = nec; m = mc + 1; ++j;
        if (nst < MAXST) sstates[nst] = make_int2(sb, eb);
        ++nst;
        if (sb >= eb) break;
        e0 = e1; e1 = e2; e2 = ev[min(j + 2, 2048)];
      }
    }
    pub_mode = mode;
    pub_nst0 = (nst < MAXST) ? nst : MAXST;
  }
  __syncthreads();

  // ---- phase 6: parallel tail emission + copies ----
  int mode = pub_mode;
  int nst0 = pub_nst0;
  if (mode == 1) {
    int j0 = pub_j0, sbF = pub_sb, mtF = pub_mt;
    int locA = NC + 1, locB = NC + 1;
    for (int j = j0 + t; j <= NC; j += NT) {
      int2 e = ev[j];
      if (e.x >= mtF && j < locA) locA = j;   // includes MINF sentinels
      if (e.y <= sbF && j < locB) locB = j;
    }
    #pragma unroll
    for (int off = 32; off > 0; off >>= 1) {
      locA = min(locA, __shfl_down(locA, off));
      locB = min(locB, __shfl_down(locB, off));
    }
    if (lane == 0) { ired[wid] = locA; ired2[wid] = locB; }
    __syncthreads();
    if (t == 0) {
      int jA = NC + 1, jB = NC + 1;
      for (int w = 0; w < 8; ++w) { jA = min(jA, ired[w]); jB = min(jB, ired2[w]); }
      int nfire, clampLast;
      if (jB < jA) { nfire = jB - j0 + 1; clampLast = 1; }
      else         { nfire = jA - j0;     clampLast = 0; }
      if (nfire < 0) nfire = 0;
      int ntot = nst0 + nfire;
      if (ntot > MAXST) ntot = MAXST;
      pub_nfire = nfire; pub_clamp = clampLast; pub_ntot = ntot;
    }
    __syncthreads();
    int nfire = pub_nfire, clampLast = pub_clamp;
    for (int i = t; i < nfire; i += NT) {
      int idx = nst0 + i;
      if (idx < MAXST) {
        int y = ev[j0 + i].y;
        ws->states[idx] = make_int2(sbF, (clampLast && i == nfire - 1) ? sbF : y);
      }
    }
    if (t == 0) ws->n_states = pub_ntot;
  } else {
    if (t == 0) ws->n_states = nst0;
  }
  for (int i = t; i < nst0; i += NT) ws->states[i] = sstates[i];
}

// ---------------- Phase 3b: evaluate quantization error for all states ----------------
__global__ void __launch_bounds__(256) k_eval(Ws* __restrict__ ws) {
  int i = blockIdx.x;
  if (i >= ws->n_states) return;
  int2 st = ws->states[i];
  float bw = ws->bin_width;
  float cnt = (float)(st.y - st.x + 1);
  float w = bw * cnt / (float)DSTN;
  int t = threadIdx.x;
  if (w == 0.0f) {
    if (t == 0) ws->norms[i] = 0.0f;
    return;
  }
  float hw = 0.5f * w;
  float hw3 = hw * hw * hw;
  float nsb = (float)st.x;
  float sum = 0.0f;
  #pragma unroll
  for (int k = 0; k < 8; ++k) {
    int j = t + 256 * k;
    float h = ws->histf[j];
    float begin = ((float)j - nsb) * bw;
    float end = begin + bw;
    float db = fminf(fmaxf(floorf(begin / w), 0.0f), (float)(DSTN - 1));
    float de = fminf(fmaxf(floorf(end / w), 0.0f), (float)(DSTN - 1));
    float density = h / bw;
    float dbc = (db + 0.5f) * w;
    float a1 = begin - dbc;
    float n1 = density * (hw3 - a1 * a1 * a1) / 3.0f;
    float nmid = density * (hw3 + hw3) / 3.0f;
    float dec = de * w + hw;
    float a3 = end - dec;
    float n3 = density * (a3 * a3 * a3 + hw3) / 3.0f;
    sum += n1 + (de - db - 1.0f) * nmid + n3;
  }
  __shared__ float red[256];
  red[t] = sum;
  __syncthreads();
  for (int off = 128; off > 0; off >>= 1) {
    if (t < off) red[t] += red[t + off];
    __syncthreads();
  }
  if (t == 0) ws->norms[i] = red[0];
}

// ---------------- Phase 3c: first norm increase -> final range ----------------
__global__ void __launch_bounds__(256) k_final(Ws* __restrict__ ws, float* __restrict__ out) {
  __shared__ int sbrk[256];
  int N = ws->n_states;
  int t = threadIdx.x;
  int loc = 0x7fffffff;
  for (int i = t + 1; i < N; i += 256) {
    if (ws->norms[i] > ws->norms[i - 1]) loc = min(loc, i);
  }
  sbrk[t] = loc;
  __syncthreads();
  for (int off = 128; off > 0; off >>= 1) {
    if (t < off) sbrk[t] = min(sbrk[t], sbrk[t + off]);
    __syncthreads();
  }
  if (t == 0) {
    int sb, eb;
    if (N == 0) { sb = 0; eb = BINS - 1; }
    else {
      int ib = sbrk[0];
      int fi = (ib != 0x7fffffff) ? (ib - 1) : (N - 1);
      int2 st = ws->states[fi];
      sb = st.x; eb = st.y;
    }
    float minv = ws->min_val, bw = ws->bin_width;
    out[0] = minv + bw * (float)sb;
    out[1] = minv + bw * (float)(eb + 1);
  }
}

extern "C" void kernel_launch(void* const* d_in, const int* in_sizes, int n_in,
                              void* d_out, int out_size, void* d_ws, size_t ws_size,
                              hipStream_t stream) {
  const float* x = (const float*)d_in[0];
  long long n = (long long)in_sizes[0];
  Ws* ws = (Ws*)d_ws;
  float* out = (float*)d_out;

  k_minmax<<<NPART, 256, 0, stream>>>(x, n, ws);
  k_minmax_final<<<1, 256, 0, stream>>>(ws, NPART);
  k_hist<<<NPART, 256, 0, stream>>>(x, n, ws);
  k_search<<<1, NT, 0, stream>>>(ws);
  k_eval<<<MAXST, 256, 0, stream>>>(ws);
  k_final<<<1, 256, 0, stream>>>(ws, out);
}